// Round 1
// baseline (4965.091 us; speedup 1.0000x reference)
//
#include <hip/hip_runtime.h>

#define N_NODES 50000
#define N_EDGES 800000
#define CEILDIV(a,b) (((a)+(b)-1)/(b))

// ---------------------------------------------------------------------------
// degree / normalization kernels (dinv depends only on dst; computed once)
// ---------------------------------------------------------------------------
__global__ __launch_bounds__(256) void k_deg_init(float* deg, int n) {
    int i = blockIdx.x * 256 + threadIdx.x;
    if (i < n) deg[i] = 1.0f;  // self-loop
}

__global__ __launch_bounds__(256) void k_deg_count(const int* __restrict__ dst,
                                                   float* deg, int e) {
    int i = blockIdx.x * 256 + threadIdx.x;
    if (i < e) unsafeAtomicAdd(&deg[dst[i]], 1.0f);
}

__global__ __launch_bounds__(256) void k_dinv(float* deg, int n) {
    int i = blockIdx.x * 256 + threadIdx.x;
    if (i < n) deg[i] = rsqrtf(deg[i]);   // deg >= 1 always (self loop)
}

// ---------------------------------------------------------------------------
// GEMM: C[n][K] = (RELU? relu(A) : A)[n][128] @ W[128][K]
// W fully in LDS, A tile in LDS, each thread computes a 4x4 micro-tile.
// ---------------------------------------------------------------------------
template<int K, int ROWS, bool RELU>
__global__ __launch_bounds__(256) void k_gemm(const float* __restrict__ A,
                                              const float* __restrict__ W,
                                              float* __restrict__ C, int n) {
    constexpr int M  = 128;        // inner dim
    constexpr int CG = K / 4;      // column groups (float4)
    __shared__ float Wl[M * K];
    __shared__ float Al[ROWS * M];

    const int tid  = threadIdx.x;
    const int row0 = blockIdx.x * ROWS;

    // stage W -> LDS (coalesced float4)
    constexpr int WV = (M * K / 4) / 256;
    const float4* W4  = (const float4*)W;
    float4*       Wl4 = (float4*)Wl;
#pragma unroll
    for (int i = 0; i < WV; ++i) Wl4[tid + i * 256] = W4[tid + i * 256];

    // stage A tile -> LDS (coalesced float4), fused ReLU, tail rows zeroed
    constexpr int AV = (ROWS * M / 4) / 256;
    float4* Al4 = (float4*)Al;
#pragma unroll
    for (int i = 0; i < AV; ++i) {
        int f  = tid + i * 256;
        int r  = f >> 5;           // 128/4 = 32 float4 per row
        int gr = row0 + r;
        float4 v;
        if (gr < n) {
            v = ((const float4*)A)[(size_t)gr * 32 + (f & 31)];
            if (RELU) {
                v.x = fmaxf(v.x, 0.f); v.y = fmaxf(v.y, 0.f);
                v.z = fmaxf(v.z, 0.f); v.w = fmaxf(v.w, 0.f);
            }
        } else {
            v = make_float4(0.f, 0.f, 0.f, 0.f);
        }
        Al4[f] = v;
    }
    __syncthreads();

    const int cg = tid % CG;       // which 4-col group
    const int rg = tid / CG;       // which 4-row group

    float acc[4][4];
#pragma unroll
    for (int a = 0; a < 4; ++a)
#pragma unroll
        for (int b = 0; b < 4; ++b) acc[a][b] = 0.f;

#pragma unroll
    for (int m = 0; m < M; m += 4) {
        float4 w0 = Wl4[(m + 0) * CG + cg];
        float4 w1 = Wl4[(m + 1) * CG + cg];
        float4 w2 = Wl4[(m + 2) * CG + cg];
        float4 w3 = Wl4[(m + 3) * CG + cg];
        const float* wp[4] = {(const float*)&w0, (const float*)&w1,
                              (const float*)&w2, (const float*)&w3};
#pragma unroll
        for (int r = 0; r < 4; ++r) {
            float4 av = Al4[(rg * 4 + r) * 32 + (m >> 2)];
            const float* ap = (const float*)&av;
#pragma unroll
            for (int mm = 0; mm < 4; ++mm) {
#pragma unroll
                for (int c = 0; c < 4; ++c)
                    acc[r][c] += ap[mm] * wp[mm][c];
            }
        }
    }

#pragma unroll
    for (int r = 0; r < 4; ++r) {
        int gr = row0 + rg * 4 + r;
        if (gr < n) {
            float4 o = make_float4(acc[r][0], acc[r][1], acc[r][2], acc[r][3]);
            ((float4*)C)[(size_t)gr * CG + cg] = o;
        }
    }
}

// ---------------------------------------------------------------------------
// aggregation init: out[i][k] = h[i][k] * dinv[i]^2  + b[k]   (self loop + bias)
// ---------------------------------------------------------------------------
template<int K>
__global__ __launch_bounds__(256) void k_agg_init(const float* __restrict__ h,
                                                  const float* __restrict__ dinv,
                                                  const float* __restrict__ b,
                                                  float* __restrict__ out, int n) {
    constexpr int KV = K / 4;
    int idx = blockIdx.x * 256 + threadIdx.x;     // float4 index
    if (idx >= n * KV) return;
    int i  = idx / KV;
    int k4 = idx % KV;
    float di = dinv[i];
    float s  = di * di;                            // = 1/deg[i]
    float4 v  = ((const float4*)h)[idx];
    float4 bb = ((const float4*)b)[k4];
    float4 o;
    o.x = v.x * s + bb.x;
    o.y = v.y * s + bb.y;
    o.z = v.z * s + bb.z;
    o.w = v.w * s + bb.w;
    ((float4*)out)[idx] = o;
}

// ---------------------------------------------------------------------------
// edge scatter: out[dst] += h[src] * dinv[src]*dinv[dst]
// K/4 threads per edge, float4 gather, 4 scalar f32 HW atomics per thread.
// ---------------------------------------------------------------------------
template<int K>
__global__ __launch_bounds__(256) void k_agg_edge(const float* __restrict__ h,
                                                  const int* __restrict__ src,
                                                  const int* __restrict__ dst,
                                                  const float* __restrict__ dinv,
                                                  float* __restrict__ out, int e) {
    constexpr int TPE = K / 4;        // threads per edge
    constexpr int EPB = 256 / TPE;    // edges per block
    int le = threadIdx.x / TPE;
    int kk = threadIdx.x % TPE;
    int ed = blockIdx.x * EPB + le;
    if (ed >= e) return;
    int s = src[ed];
    int d = dst[ed];
    float norm = dinv[s] * dinv[d];
    float4 v = ((const float4*)h)[(size_t)s * TPE + kk];
    float* o = out + (size_t)d * K + (size_t)kk * 4;
    unsafeAtomicAdd(o + 0, v.x * norm);
    unsafeAtomicAdd(o + 1, v.y * norm);
    unsafeAtomicAdd(o + 2, v.z * norm);
    unsafeAtomicAdd(o + 3, v.w * norm);
}

// ---------------------------------------------------------------------------
extern "C" void kernel_launch(void* const* d_in, const int* in_sizes, int n_in,
                              void* d_out, int out_size, void* d_ws, size_t ws_size,
                              hipStream_t stream) {
    const float* x  = (const float*)d_in[0];
    const int*   ei = (const int*)d_in[1];          // [2][N_EDGES]: src row then dst row
    const float* W1 = (const float*)d_in[2];
    const float* b1 = (const float*)d_in[3];
    const float* W2 = (const float*)d_in[4];
    const float* b2 = (const float*)d_in[5];
    const float* W3 = (const float*)d_in[6];
    const float* b3 = (const float*)d_in[7];
    float* out = (float*)d_out;

    const int* src = ei;
    const int* dst = ei + N_EDGES;

    // workspace layout
    char* ws = (char*)d_ws;
    float* dinv = (float*)ws;                                    // 50000 f32
    float* hbuf = (float*)(ws + 256 * 1024);                     // 50000*128 f32
    float* abuf = (float*)(ws + 256 * 1024 + (size_t)N_NODES * 128 * 4);

    const int n = N_NODES, e = N_EDGES;

    // --- normalization (shared across layers) ---
    k_deg_init<<<CEILDIV(n, 256), 256, 0, stream>>>(dinv, n);
    k_deg_count<<<CEILDIV(e, 256), 256, 0, stream>>>(dst, dinv, e);
    k_dinv<<<CEILDIV(n, 256), 256, 0, stream>>>(dinv, n);

    // --- layer 1: h = x @ W1 ; a1 = scatter(h) + b1 ---
    k_gemm<128, 32, false><<<CEILDIV(n, 32), 256, 0, stream>>>(x, W1, hbuf, n);
    k_agg_init<128><<<CEILDIV(n * 32, 256), 256, 0, stream>>>(hbuf, dinv, b1, abuf, n);
    k_agg_edge<128><<<CEILDIV(e, 8), 256, 0, stream>>>(hbuf, src, dst, dinv, abuf, e);

    // --- layer 2: h = relu(a1) @ W2 ; a2 = scatter(h) + b2 (a2 overwrites via hbuf swap) ---
    k_gemm<128, 32, true><<<CEILDIV(n, 32), 256, 0, stream>>>(abuf, W2, hbuf, n);
    // a2 goes back into abuf (a1 dead after gemm2 completes; stream-ordered)
    k_agg_init<128><<<CEILDIV(n * 32, 256), 256, 0, stream>>>(hbuf, dinv, b2, abuf, n);
    k_agg_edge<128><<<CEILDIV(e, 8), 256, 0, stream>>>(hbuf, src, dst, dinv, abuf, e);

    // --- layer 3: h = relu(a2) @ W3 (K=64) ; out = scatter(h) + b3, no relu ---
    k_gemm<64, 64, true><<<CEILDIV(n, 64), 256, 0, stream>>>(abuf, W3, hbuf, n);
    k_agg_init<64><<<CEILDIV(n * 16, 256), 256, 0, stream>>>(hbuf, dinv, b3, out, n);
    k_agg_edge<64><<<CEILDIV(e, 16), 256, 0, stream>>>(hbuf, src, dst, dinv, out, e);
}

// Round 2
// 1940.300 us; speedup vs baseline: 2.5589x; 2.5589x over previous
//
#include <hip/hip_runtime.h>

#define N_NODES 50000
#define N_EDGES 800000
#define CEILDIV(a,b) (((a)+(b)-1)/(b))

// ---------------------------------------------------------------------------
// CSR build (once per call, shared by all 3 layers)
// ---------------------------------------------------------------------------
__global__ __launch_bounds__(256) void k_deg_count(const int* __restrict__ dst,
                                                   int* __restrict__ degcnt, int e) {
    int i = blockIdx.x * 256 + threadIdx.x;
    if (i < e) atomicAdd(&degcnt[dst[i]], 1);
}

// single-block exclusive scan over degcnt -> rowstart; also dinv = rsqrt(deg+1)
__global__ __launch_bounds__(256) void k_scan(const int* __restrict__ degcnt,
                                              int* __restrict__ rowstart,
                                              float* __restrict__ dinv, int n) {
    __shared__ int part[256];
    const int tid = threadIdx.x;
    const int CH = CEILDIV(N_NODES, 256);
    const int base = tid * CH;
    int s = 0;
    for (int i = 0; i < CH; ++i) {
        int idx = base + i;
        if (idx < n) s += degcnt[idx];
    }
    part[tid] = s;
    __syncthreads();
    // Hillis-Steele inclusive scan of 256 partials
    for (int off = 1; off < 256; off <<= 1) {
        int v = (tid >= off) ? part[tid - off] : 0;
        __syncthreads();
        part[tid] += v;
        __syncthreads();
    }
    int run = (tid == 0) ? 0 : part[tid - 1];
    for (int i = 0; i < CH; ++i) {
        int idx = base + i;
        if (idx < n) {
            rowstart[idx] = run;
            int d = degcnt[idx];
            run += d;
            dinv[idx] = rsqrtf((float)(d + 1));   // +1 self loop
        }
    }
    if (tid == 255) rowstart[n] = run;
}

__global__ __launch_bounds__(256) void k_bin(const int* __restrict__ src,
                                             const int* __restrict__ dst,
                                             const int* __restrict__ rowstart,
                                             int* __restrict__ cursor,
                                             int* __restrict__ esrc, int e) {
    int i = blockIdx.x * 256 + threadIdx.x;
    if (i < e) {
        int d = dst[i];
        int pos = rowstart[d] + atomicAdd(&cursor[d], 1);
        esrc[pos] = src[i];
    }
}

// ---------------------------------------------------------------------------
// GEMM: C[n][K] = (RELU? relu(A) : A)[n][128] @ W[128][K]
// ---------------------------------------------------------------------------
template<int K, int ROWS, bool RELU>
__global__ __launch_bounds__(256) void k_gemm(const float* __restrict__ A,
                                              const float* __restrict__ W,
                                              float* __restrict__ C, int n) {
    constexpr int M  = 128;
    constexpr int CG = K / 4;
    __shared__ float Wl[M * K];
    __shared__ float Al[ROWS * M];

    const int tid  = threadIdx.x;
    const int row0 = blockIdx.x * ROWS;

    constexpr int WV = (M * K / 4) / 256;
    const float4* W4  = (const float4*)W;
    float4*       Wl4 = (float4*)Wl;
#pragma unroll
    for (int i = 0; i < WV; ++i) Wl4[tid + i * 256] = W4[tid + i * 256];

    constexpr int AV = (ROWS * M / 4) / 256;
    float4* Al4 = (float4*)Al;
#pragma unroll
    for (int i = 0; i < AV; ++i) {
        int f  = tid + i * 256;
        int r  = f >> 5;
        int gr = row0 + r;
        float4 v;
        if (gr < n) {
            v = ((const float4*)A)[(size_t)gr * 32 + (f & 31)];
            if (RELU) {
                v.x = fmaxf(v.x, 0.f); v.y = fmaxf(v.y, 0.f);
                v.z = fmaxf(v.z, 0.f); v.w = fmaxf(v.w, 0.f);
            }
        } else {
            v = make_float4(0.f, 0.f, 0.f, 0.f);
        }
        Al4[f] = v;
    }
    __syncthreads();

    const int cg = tid % CG;
    const int rg = tid / CG;

    float acc[4][4];
#pragma unroll
    for (int a = 0; a < 4; ++a)
#pragma unroll
        for (int b = 0; b < 4; ++b) acc[a][b] = 0.f;

#pragma unroll
    for (int m = 0; m < M; m += 4) {
        float4 w0 = Wl4[(m + 0) * CG + cg];
        float4 w1 = Wl4[(m + 1) * CG + cg];
        float4 w2 = Wl4[(m + 2) * CG + cg];
        float4 w3 = Wl4[(m + 3) * CG + cg];
        const float* wp[4] = {(const float*)&w0, (const float*)&w1,
                              (const float*)&w2, (const float*)&w3};
#pragma unroll
        for (int r = 0; r < 4; ++r) {
            float4 av = Al4[(rg * 4 + r) * 32 + (m >> 2)];
            const float* ap = (const float*)&av;
#pragma unroll
            for (int mm = 0; mm < 4; ++mm) {
#pragma unroll
                for (int c = 0; c < 4; ++c)
                    acc[r][c] += ap[mm] * wp[mm][c];
            }
        }
    }

#pragma unroll
    for (int r = 0; r < 4; ++r) {
        int gr = row0 + rg * 4 + r;
        if (gr < n) {
            float4 o = make_float4(acc[r][0], acc[r][1], acc[r][2], acc[r][3]);
            ((float4*)C)[(size_t)gr * CG + cg] = o;
        }
    }
}

// ---------------------------------------------------------------------------
// Gather aggregation: one wave per destination node.
//   out[i][:] = b + h[i]/deg[i] + sum_{e: dst=i} h[src_e][:] * dinv[src_e]*dinv[i]
// K=128: each lane owns 2 cols (float2). K=64: 1 col.
// ---------------------------------------------------------------------------
template<int K>
__global__ __launch_bounds__(256) void k_aggregate(const float* __restrict__ h,
                                                   const int* __restrict__ rowstart,
                                                   const int* __restrict__ esrc,
                                                   const float* __restrict__ dinv,
                                                   const float* __restrict__ b,
                                                   float* __restrict__ out, int n) {
    constexpr int VEC = K / 64;           // floats per lane
    const int wave = threadIdx.x >> 6;
    const int lane = threadIdx.x & 63;
    const int node = blockIdx.x * 4 + wave;
    if (node >= n) return;

    const float dd = dinv[node];

    float acc[VEC];
    if (VEC == 2) {
        float2 hv = ((const float2*)h)[(size_t)node * 64 + lane];
        float2 bv = ((const float2*)b)[lane];
        acc[0] = hv.x * dd * dd + bv.x;
        acc[1] = hv.y * dd * dd + bv.y;
    } else {
        acc[0] = h[(size_t)node * K + lane] * dd * dd + b[lane];
    }

    int row = rowstart[node];
    const int end = rowstart[node + 1];
    while (row < end) {
        int cnt = end - row;
        if (cnt > 64) cnt = 64;
        // batch-load up to 64 edge srcs + their dinv, broadcast via shfl
        int   s_l  = (lane < cnt) ? esrc[row + lane] : 0;
        float nv_l = (lane < cnt) ? dinv[s_l] * dd : 0.f;
        for (int j = 0; j < cnt; ++j) {
            int   s   = __shfl(s_l, j);
            float nrm = __shfl(nv_l, j);
            if (VEC == 2) {
                float2 hv = ((const float2*)h)[(size_t)s * 64 + lane];
                acc[0] += hv.x * nrm;
                acc[1] += hv.y * nrm;
            } else {
                acc[0] += h[(size_t)s * K + lane] * nrm;
            }
        }
        row += cnt;
    }

    if (VEC == 2) {
        ((float2*)out)[(size_t)node * 64 + lane] = make_float2(acc[0], acc[1]);
    } else {
        out[(size_t)node * K + lane] = acc[0];
    }
}

// ---------------------------------------------------------------------------
extern "C" void kernel_launch(void* const* d_in, const int* in_sizes, int n_in,
                              void* d_out, int out_size, void* d_ws, size_t ws_size,
                              hipStream_t stream) {
    const float* x  = (const float*)d_in[0];
    const int*   ei = (const int*)d_in[1];
    const float* W1 = (const float*)d_in[2];
    const float* b1 = (const float*)d_in[3];
    const float* W2 = (const float*)d_in[4];
    const float* b2 = (const float*)d_in[5];
    const float* W3 = (const float*)d_in[6];
    const float* b3 = (const float*)d_in[7];
    float* out = (float*)d_out;

    const int* src = ei;
    const int* dst = ei + N_EDGES;

    // workspace layout (256B aligned chunks)
    char* ws = (char*)d_ws;
    size_t off = 0;
    auto alloc = [&](size_t bytes) {
        void* p = ws + off;
        off += (bytes + 255) & ~(size_t)255;
        return p;
    };
    int*   degcnt   = (int*)alloc(N_NODES * 4);
    int*   cursor   = (int*)alloc(N_NODES * 4);
    int*   rowstart = (int*)alloc((N_NODES + 1) * 4);
    float* dinv     = (float*)alloc(N_NODES * 4);
    int*   esrc     = (int*)alloc((size_t)N_EDGES * 4);
    float* hbuf     = (float*)alloc((size_t)N_NODES * 128 * 4);
    float* abuf     = (float*)alloc((size_t)N_NODES * 128 * 4);

    const int n = N_NODES, e = N_EDGES;

    // --- CSR build (once; reused by all layers) ---
    hipMemsetAsync(degcnt, 0, N_NODES * 4, stream);
    hipMemsetAsync(cursor, 0, N_NODES * 4, stream);
    k_deg_count<<<CEILDIV(e, 256), 256, 0, stream>>>(dst, degcnt, e);
    k_scan<<<1, 256, 0, stream>>>(degcnt, rowstart, dinv, n);
    k_bin<<<CEILDIV(e, 256), 256, 0, stream>>>(src, dst, rowstart, cursor, esrc, e);

    // --- layer 1 ---
    k_gemm<128, 32, false><<<CEILDIV(n, 32), 256, 0, stream>>>(x, W1, hbuf, n);
    k_aggregate<128><<<CEILDIV(n, 4), 256, 0, stream>>>(hbuf, rowstart, esrc, dinv, b1, abuf, n);

    // --- layer 2 ---
    k_gemm<128, 32, true><<<CEILDIV(n, 32), 256, 0, stream>>>(abuf, W2, hbuf, n);
    k_aggregate<128><<<CEILDIV(n, 4), 256, 0, stream>>>(hbuf, rowstart, esrc, dinv, b2, abuf, n);

    // --- layer 3 (K=64) ---
    k_gemm<64, 64, true><<<CEILDIV(n, 64), 256, 0, stream>>>(abuf, W3, hbuf, n);
    k_aggregate<64><<<CEILDIV(n, 4), 256, 0, stream>>>(hbuf, rowstart, esrc, dinv, b3, out, n);
}

// Round 4
// 1813.393 us; speedup vs baseline: 2.7380x; 1.0700x over previous
//
#include <hip/hip_runtime.h>

#define N_NODES 50000
#define N_EDGES 800000
#define CEILDIV(a,b) (((a)+(b)-1)/(b))

// ---------------------------------------------------------------------------
// CSR build (once per call, shared by all 3 layers)
// ---------------------------------------------------------------------------
__global__ __launch_bounds__(256) void k_deg_count(const int* __restrict__ dst,
                                                   int* __restrict__ degcnt, int e) {
    int i = blockIdx.x * 256 + threadIdx.x;
    if (i < e) atomicAdd(&degcnt[dst[i]], 1);
}

// single-block exclusive scan over degcnt -> rowstart; also dinv = rsqrt(deg+1)
__global__ __launch_bounds__(256) void k_scan(const int* __restrict__ degcnt,
                                              int* __restrict__ rowstart,
                                              float* __restrict__ dinv, int n) {
    __shared__ int part[256];
    const int tid = threadIdx.x;
    const int CH = CEILDIV(N_NODES, 256);
    const int base = tid * CH;
    int s = 0;
    for (int i = 0; i < CH; ++i) {
        int idx = base + i;
        if (idx < n) s += degcnt[idx];
    }
    part[tid] = s;
    __syncthreads();
    for (int off = 1; off < 256; off <<= 1) {
        int v = (tid >= off) ? part[tid - off] : 0;
        __syncthreads();
        part[tid] += v;
        __syncthreads();
    }
    int run = (tid == 0) ? 0 : part[tid - 1];
    for (int i = 0; i < CH; ++i) {
        int idx = base + i;
        if (idx < n) {
            rowstart[idx] = run;
            int d = degcnt[idx];
            run += d;
            dinv[idx] = rsqrtf((float)(d + 1));   // +1 self loop
        }
    }
    if (tid == 255) rowstart[n] = run;
}

__global__ __launch_bounds__(256) void k_bin(const int* __restrict__ src,
                                             const int* __restrict__ dst,
                                             const int* __restrict__ rowstart,
                                             int* __restrict__ cursor,
                                             int* __restrict__ esrc, int e) {
    int i = blockIdx.x * 256 + threadIdx.x;
    if (i < e) {
        int d = dst[i];
        int pos = rowstart[d] + atomicAdd(&cursor[d], 1);
        esrc[pos] = src[i];
    }
}

// ---------------------------------------------------------------------------
// GEMM: C[n][K] = (RELU? relu(A) : A)[n][128] @ W[128][K]
// Fully static inner loop (no address-taken locals -> no scratch).
// ---------------------------------------------------------------------------
template<int K, int ROWS, bool RELU>
__global__ __launch_bounds__(256) void k_gemm(const float* __restrict__ A,
                                              const float* __restrict__ W,
                                              float* __restrict__ C, int n) {
    constexpr int M  = 128;
    constexpr int CG = K / 4;      // float4 column groups
    __shared__ float4 Wl4[M * CG];
    __shared__ float4 Al4[ROWS * 32];

    const int tid  = threadIdx.x;
    const int row0 = blockIdx.x * ROWS;

    // stage W -> LDS
    constexpr int WV = (M * CG) / 256;
    const float4* W4 = (const float4*)W;
#pragma unroll
    for (int i = 0; i < WV; ++i) Wl4[tid + i * 256] = W4[tid + i * 256];

    // stage A tile -> LDS (fused ReLU; tail rows zeroed)
    constexpr int AV = (ROWS * 32) / 256;
#pragma unroll
    for (int i = 0; i < AV; ++i) {
        int f  = tid + i * 256;
        int r  = f >> 5;
        int gr = row0 + r;
        float4 v;
        if (gr < n) {
            v = ((const float4*)A)[(size_t)gr * 32 + (f & 31)];
            if (RELU) {
                v.x = fmaxf(v.x, 0.f); v.y = fmaxf(v.y, 0.f);
                v.z = fmaxf(v.z, 0.f); v.w = fmaxf(v.w, 0.f);
            }
        } else {
            v = make_float4(0.f, 0.f, 0.f, 0.f);
        }
        Al4[f] = v;
    }
    __syncthreads();

    const int cg = tid % CG;
    const int rg = tid / CG;

    float4 acc0 = make_float4(0.f, 0.f, 0.f, 0.f);
    float4 acc1 = acc0, acc2 = acc0, acc3 = acc0;

#pragma unroll
    for (int m4 = 0; m4 < 32; ++m4) {
        const float4 w0 = Wl4[(m4 * 4 + 0) * CG + cg];
        const float4 w1 = Wl4[(m4 * 4 + 1) * CG + cg];
        const float4 w2 = Wl4[(m4 * 4 + 2) * CG + cg];
        const float4 w3 = Wl4[(m4 * 4 + 3) * CG + cg];

#define ROW_STEP(AV_, ACC_)                                   \
        {                                                     \
            const float4 a_ = (AV_);                          \
            ACC_.x = fmaf(a_.x, w0.x, ACC_.x);                \
            ACC_.x = fmaf(a_.y, w1.x, ACC_.x);                \
            ACC_.x = fmaf(a_.z, w2.x, ACC_.x);                \
            ACC_.x = fmaf(a_.w, w3.x, ACC_.x);                \
            ACC_.y = fmaf(a_.x, w0.y, ACC_.y);                \
            ACC_.y = fmaf(a_.y, w1.y, ACC_.y);                \
            ACC_.y = fmaf(a_.z, w2.y, ACC_.y);                \
            ACC_.y = fmaf(a_.w, w3.y, ACC_.y);                \
            ACC_.z = fmaf(a_.x, w0.z, ACC_.z);                \
            ACC_.z = fmaf(a_.y, w1.z, ACC_.z);                \
            ACC_.z = fmaf(a_.z, w2.z, ACC_.z);                \
            ACC_.z = fmaf(a_.w, w3.z, ACC_.z);                \
            ACC_.w = fmaf(a_.x, w0.w, ACC_.w);                \
            ACC_.w = fmaf(a_.y, w1.w, ACC_.w);                \
            ACC_.w = fmaf(a_.z, w2.w, ACC_.w);                \
            ACC_.w = fmaf(a_.w, w3.w, ACC_.w);                \
        }

        ROW_STEP(Al4[(rg * 4 + 0) * 32 + m4], acc0);
        ROW_STEP(Al4[(rg * 4 + 1) * 32 + m4], acc1);
        ROW_STEP(Al4[(rg * 4 + 2) * 32 + m4], acc2);
        ROW_STEP(Al4[(rg * 4 + 3) * 32 + m4], acc3);
#undef ROW_STEP
    }

    {
        int gr = row0 + rg * 4;
        if (gr + 0 < n) ((float4*)C)[(size_t)(gr + 0) * CG + cg] = acc0;
        if (gr + 1 < n) ((float4*)C)[(size_t)(gr + 1) * CG + cg] = acc1;
        if (gr + 2 < n) ((float4*)C)[(size_t)(gr + 2) * CG + cg] = acc2;
        if (gr + 3 < n) ((float4*)C)[(size_t)(gr + 3) * CG + cg] = acc3;
    }
}

// ---------------------------------------------------------------------------
// Gather aggregation: one wave per destination node.
// ---------------------------------------------------------------------------
template<int K>
__global__ __launch_bounds__(256) void k_aggregate(const float* __restrict__ h,
                                                   const int* __restrict__ rowstart,
                                                   const int* __restrict__ esrc,
                                                   const float* __restrict__ dinv,
                                                   const float* __restrict__ b,
                                                   float* __restrict__ out, int n) {
    constexpr int VEC = K / 64;           // floats per lane
    const int wave = threadIdx.x >> 6;
    const int lane = threadIdx.x & 63;
    const int node = blockIdx.x * 4 + wave;
    if (node >= n) return;

    const float dd = dinv[node];

    float acc0, acc1;
    if (VEC == 2) {
        float2 hv = ((const float2*)h)[(size_t)node * 64 + lane];
        float2 bv = ((const float2*)b)[lane];
        acc0 = hv.x * dd * dd + bv.x;
        acc1 = hv.y * dd * dd + bv.y;
    } else {
        acc0 = h[(size_t)node * K + lane] * dd * dd + b[lane];
        acc1 = 0.f;
    }

    int row = rowstart[node];
    const int end = rowstart[node + 1];
    while (row < end) {
        int cnt = end - row;
        if (cnt > 64) cnt = 64;
        int   s_l  = (lane < cnt) ? esrc[row + lane] : 0;
        float nv_l = (lane < cnt) ? dinv[s_l] * dd : 0.f;
        for (int j = 0; j < cnt; ++j) {
            int   s   = __shfl(s_l, j);
            float nrm = __shfl(nv_l, j);
            if (VEC == 2) {
                float2 hv = ((const float2*)h)[(size_t)s * 64 + lane];
                acc0 += hv.x * nrm;
                acc1 += hv.y * nrm;
            } else {
                acc0 += h[(size_t)s * K + lane] * nrm;
            }
        }
        row += cnt;
    }

    if (VEC == 2) {
        ((float2*)out)[(size_t)node * 64 + lane] = make_float2(acc0, acc1);
    } else {
        out[(size_t)node * K + lane] = acc0;
    }
}

// ---------------------------------------------------------------------------
extern "C" void kernel_launch(void* const* d_in, const int* in_sizes, int n_in,
                              void* d_out, int out_size, void* d_ws, size_t ws_size,
                              hipStream_t stream) {
    const float* x  = (const float*)d_in[0];
    const int*   ei = (const int*)d_in[1];
    const float* W1 = (const float*)d_in[2];
    const float* b1 = (const float*)d_in[3];
    const float* W2 = (const float*)d_in[4];
    const float* b2 = (const float*)d_in[5];
    const float* W3 = (const float*)d_in[6];
    const float* b3 = (const float*)d_in[7];
    float* out = (float*)d_out;

    const int* src = ei;
    const int* dst = ei + N_EDGES;

    char* ws = (char*)d_ws;
    size_t off = 0;
    auto alloc = [&](size_t bytes) {
        void* p = ws + off;
        off += (bytes + 255) & ~(size_t)255;
        return p;
    };
    int*   degcnt   = (int*)alloc(N_NODES * 4);
    int*   cursor   = (int*)alloc(N_NODES * 4);
    int*   rowstart = (int*)alloc((N_NODES + 1) * 4);
    float* dinv     = (float*)alloc(N_NODES * 4);
    int*   esrc     = (int*)alloc((size_t)N_EDGES * 4);
    float* hbuf     = (float*)alloc((size_t)N_NODES * 128 * 4);
    float* abuf     = (float*)alloc((size_t)N_NODES * 128 * 4);

    const int n = N_NODES, e = N_EDGES;

    // --- CSR build (once; reused by all layers) ---
    hipMemsetAsync(degcnt, 0, N_NODES * 4, stream);
    hipMemsetAsync(cursor, 0, N_NODES * 4, stream);
    k_deg_count<<<CEILDIV(e, 256), 256, 0, stream>>>(dst, degcnt, e);
    k_scan<<<1, 256, 0, stream>>>(degcnt, rowstart, dinv, n);
    k_bin<<<CEILDIV(e, 256), 256, 0, stream>>>(src, dst, rowstart, cursor, esrc, e);

    // --- layer 1 ---
    k_gemm<128, 32, false><<<CEILDIV(n, 32), 256, 0, stream>>>(x, W1, hbuf, n);
    k_aggregate<128><<<CEILDIV(n, 4), 256, 0, stream>>>(hbuf, rowstart, esrc, dinv, b1, abuf, n);

    // --- layer 2 ---
    k_gemm<128, 32, true><<<CEILDIV(n, 32), 256, 0, stream>>>(abuf, W2, hbuf, n);
    k_aggregate<128><<<CEILDIV(n, 4), 256, 0, stream>>>(hbuf, rowstart, esrc, dinv, b2, abuf, n);

    // --- layer 3 (K=64) ---
    k_gemm<64, 64, true><<<CEILDIV(n, 64), 256, 0, stream>>>(abuf, W3, hbuf, n);
    k_aggregate<64><<<CEILDIV(n, 4), 256, 0, stream>>>(hbuf, rowstart, esrc, dinv, b3, out, n);
}

// Round 6
// 561.782 us; speedup vs baseline: 8.8381x; 3.2279x over previous
//
#include <hip/hip_runtime.h>

#define N_NODES 50000
#define N_EDGES 800000
#define CEILDIV(a,b) (((a)+(b)-1)/(b))

// ---------------------------------------------------------------------------
// CSR build (once per call, shared by all 3 layers)
// ---------------------------------------------------------------------------
__global__ __launch_bounds__(256) void k_deg_count(const int* __restrict__ dst,
                                                   int* __restrict__ degcnt, int e) {
    int i = blockIdx.x * 256 + threadIdx.x;
    if (i < e) atomicAdd(&degcnt[dst[i]], 1);
}

// single-block exclusive scan over degcnt -> rowstart; also dinv = rsqrt(deg+1)
__global__ __launch_bounds__(256) void k_scan(const int* __restrict__ degcnt,
                                              int* __restrict__ rowstart,
                                              float* __restrict__ dinv, int n) {
    __shared__ int part[256];
    const int tid = threadIdx.x;
    const int CH = CEILDIV(N_NODES, 256);
    const int base = tid * CH;
    int s = 0;
    for (int i = 0; i < CH; ++i) {
        int idx = base + i;
        if (idx < n) s += degcnt[idx];
    }
    part[tid] = s;
    __syncthreads();
    for (int off = 1; off < 256; off <<= 1) {
        int v = (tid >= off) ? part[tid - off] : 0;
        __syncthreads();
        part[tid] += v;
        __syncthreads();
    }
    int run = (tid == 0) ? 0 : part[tid - 1];
    for (int i = 0; i < CH; ++i) {
        int idx = base + i;
        if (idx < n) {
            rowstart[idx] = run;
            int d = degcnt[idx];
            run += d;
            dinv[idx] = rsqrtf((float)(d + 1));   // +1 self loop
        }
    }
    if (tid == 255) rowstart[n] = run;
}

__global__ __launch_bounds__(256) void k_bin(const int* __restrict__ src,
                                             const int* __restrict__ dst,
                                             const int* __restrict__ rowstart,
                                             int* __restrict__ cursor,
                                             int* __restrict__ esrc, int e) {
    int i = blockIdx.x * 256 + threadIdx.x;
    if (i < e) {
        int d = dst[i];
        int pos = rowstart[d] + atomicAdd(&cursor[d], 1);
        esrc[pos] = src[i];
    }
}

// ---------------------------------------------------------------------------
// GEMM: C[n][K] = (RELU? relu(A) : A)[n][128] @ W[128][K]
// Static accumulator access + BOUNDED unroll (full unroll of the 32-iter
// K-loop made the scheduler hoist 256 ds_reads -> 256 VGPR + scratch spill).
// ---------------------------------------------------------------------------
template<int K, int ROWS, bool RELU>
__global__ __launch_bounds__(256) void k_gemm(const float* __restrict__ A,
                                              const float* __restrict__ W,
                                              float* __restrict__ C, int n) {
    constexpr int M  = 128;
    constexpr int CG = K / 4;      // float4 column groups
    __shared__ float4 Wl4[M * CG];
    __shared__ float4 Al4[ROWS * 32];

    const int tid  = threadIdx.x;
    const int row0 = blockIdx.x * ROWS;

    // stage W -> LDS
    constexpr int WV = (M * CG) / 256;
    const float4* W4 = (const float4*)W;
#pragma unroll
    for (int i = 0; i < WV; ++i) Wl4[tid + i * 256] = W4[tid + i * 256];

    // stage A tile -> LDS (fused ReLU; tail rows zeroed)
    constexpr int AV = (ROWS * 32) / 256;
#pragma unroll
    for (int i = 0; i < AV; ++i) {
        int f  = tid + i * 256;
        int r  = f >> 5;
        int gr = row0 + r;
        float4 v;
        if (gr < n) {
            v = ((const float4*)A)[(size_t)gr * 32 + (f & 31)];
            if (RELU) {
                v.x = fmaxf(v.x, 0.f); v.y = fmaxf(v.y, 0.f);
                v.z = fmaxf(v.z, 0.f); v.w = fmaxf(v.w, 0.f);
            }
        } else {
            v = make_float4(0.f, 0.f, 0.f, 0.f);
        }
        Al4[f] = v;
    }
    __syncthreads();

    const int cg = tid % CG;
    const int rg = tid / CG;

    float4 acc0 = make_float4(0.f, 0.f, 0.f, 0.f);
    float4 acc1 = acc0, acc2 = acc0, acc3 = acc0;

#pragma unroll 2
    for (int m4 = 0; m4 < 32; ++m4) {
        const float4 w0 = Wl4[(m4 * 4 + 0) * CG + cg];
        const float4 w1 = Wl4[(m4 * 4 + 1) * CG + cg];
        const float4 w2 = Wl4[(m4 * 4 + 2) * CG + cg];
        const float4 w3 = Wl4[(m4 * 4 + 3) * CG + cg];

#define ROW_STEP(AV_, ACC_)                                   \
        {                                                     \
            const float4 a_ = (AV_);                          \
            ACC_.x = fmaf(a_.x, w0.x, ACC_.x);                \
            ACC_.x = fmaf(a_.y, w1.x, ACC_.x);                \
            ACC_.x = fmaf(a_.z, w2.x, ACC_.x);                \
            ACC_.x = fmaf(a_.w, w3.x, ACC_.x);                \
            ACC_.y = fmaf(a_.x, w0.y, ACC_.y);                \
            ACC_.y = fmaf(a_.y, w1.y, ACC_.y);                \
            ACC_.y = fmaf(a_.z, w2.y, ACC_.y);                \
            ACC_.y = fmaf(a_.w, w3.y, ACC_.y);                \
            ACC_.z = fmaf(a_.x, w0.z, ACC_.z);                \
            ACC_.z = fmaf(a_.y, w1.z, ACC_.z);                \
            ACC_.z = fmaf(a_.z, w2.z, ACC_.z);                \
            ACC_.z = fmaf(a_.w, w3.z, ACC_.z);                \
            ACC_.w = fmaf(a_.x, w0.w, ACC_.w);                \
            ACC_.w = fmaf(a_.y, w1.w, ACC_.w);                \
            ACC_.w = fmaf(a_.z, w2.w, ACC_.w);                \
            ACC_.w = fmaf(a_.w, w3.w, ACC_.w);                \
        }

        ROW_STEP(Al4[(rg * 4 + 0) * 32 + m4], acc0);
        ROW_STEP(Al4[(rg * 4 + 1) * 32 + m4], acc1);
        ROW_STEP(Al4[(rg * 4 + 2) * 32 + m4], acc2);
        ROW_STEP(Al4[(rg * 4 + 3) * 32 + m4], acc3);
#undef ROW_STEP
    }

    {
        int gr = row0 + rg * 4;
        if (gr + 0 < n) ((float4*)C)[(size_t)(gr + 0) * CG + cg] = acc0;
        if (gr + 1 < n) ((float4*)C)[(size_t)(gr + 1) * CG + cg] = acc1;
        if (gr + 2 < n) ((float4*)C)[(size_t)(gr + 2) * CG + cg] = acc2;
        if (gr + 3 < n) ((float4*)C)[(size_t)(gr + 3) * CG + cg] = acc3;
    }
}

// ---------------------------------------------------------------------------
// Gather aggregation: one wave per destination node.
// ---------------------------------------------------------------------------
template<int K>
__global__ __launch_bounds__(256) void k_aggregate(const float* __restrict__ h,
                                                   const int* __restrict__ rowstart,
                                                   const int* __restrict__ esrc,
                                                   const float* __restrict__ dinv,
                                                   const float* __restrict__ b,
                                                   float* __restrict__ out, int n) {
    constexpr int VEC = K / 64;           // floats per lane
    const int wave = threadIdx.x >> 6;
    const int lane = threadIdx.x & 63;
    const int node = blockIdx.x * 4 + wave;
    if (node >= n) return;

    const float dd = dinv[node];

    float acc0, acc1;
    if (VEC == 2) {
        float2 hv = ((const float2*)h)[(size_t)node * 64 + lane];
        float2 bv = ((const float2*)b)[lane];
        acc0 = hv.x * dd * dd + bv.x;
        acc1 = hv.y * dd * dd + bv.y;
    } else {
        acc0 = h[(size_t)node * K + lane] * dd * dd + b[lane];
        acc1 = 0.f;
    }

    int row = rowstart[node];
    const int end = rowstart[node + 1];
    while (row < end) {
        int cnt = end - row;
        if (cnt > 64) cnt = 64;
        int   s_l  = (lane < cnt) ? esrc[row + lane] : 0;
        float nv_l = (lane < cnt) ? dinv[s_l] * dd : 0.f;
        for (int j = 0; j < cnt; ++j) {
            int   s   = __shfl(s_l, j);
            float nrm = __shfl(nv_l, j);
            if (VEC == 2) {
                float2 hv = ((const float2*)h)[(size_t)s * 64 + lane];
                acc0 += hv.x * nrm;
                acc1 += hv.y * nrm;
            } else {
                acc0 += h[(size_t)s * K + lane] * nrm;
            }
        }
        row += cnt;
    }

    if (VEC == 2) {
        ((float2*)out)[(size_t)node * 64 + lane] = make_float2(acc0, acc1);
    } else {
        out[(size_t)node * K + lane] = acc0;
    }
}

// ---------------------------------------------------------------------------
extern "C" void kernel_launch(void* const* d_in, const int* in_sizes, int n_in,
                              void* d_out, int out_size, void* d_ws, size_t ws_size,
                              hipStream_t stream) {
    const float* x  = (const float*)d_in[0];
    const int*   ei = (const int*)d_in[1];
    const float* W1 = (const float*)d_in[2];
    const float* b1 = (const float*)d_in[3];
    const float* W2 = (const float*)d_in[4];
    const float* b2 = (const float*)d_in[5];
    const float* W3 = (const float*)d_in[6];
    const float* b3 = (const float*)d_in[7];
    float* out = (float*)d_out;

    const int* src = ei;
    const int* dst = ei + N_EDGES;

    char* ws = (char*)d_ws;
    size_t off = 0;
    auto alloc = [&](size_t bytes) {
        void* p = ws + off;
        off += (bytes + 255) & ~(size_t)255;
        return p;
    };
    int*   degcnt   = (int*)alloc(N_NODES * 4);
    int*   cursor   = (int*)alloc(N_NODES * 4);
    int*   rowstart = (int*)alloc((N_NODES + 1) * 4);
    float* dinv     = (float*)alloc(N_NODES * 4);
    int*   esrc     = (int*)alloc((size_t)N_EDGES * 4);
    float* hbuf     = (float*)alloc((size_t)N_NODES * 128 * 4);
    float* abuf     = (float*)alloc((size_t)N_NODES * 128 * 4);

    const int n = N_NODES, e = N_EDGES;

    // --- CSR build (once; reused by all layers) ---
    hipMemsetAsync(degcnt, 0, N_NODES * 4, stream);
    hipMemsetAsync(cursor, 0, N_NODES * 4, stream);
    k_deg_count<<<CEILDIV(e, 256), 256, 0, stream>>>(dst, degcnt, e);
    k_scan<<<1, 256, 0, stream>>>(degcnt, rowstart, dinv, n);
    k_bin<<<CEILDIV(e, 256), 256, 0, stream>>>(src, dst, rowstart, cursor, esrc, e);

    // --- layer 1 ---
    k_gemm<128, 32, false><<<CEILDIV(n, 32), 256, 0, stream>>>(x, W1, hbuf, n);
    k_aggregate<128><<<CEILDIV(n, 4), 256, 0, stream>>>(hbuf, rowstart, esrc, dinv, b1, abuf, n);

    // --- layer 2 ---
    k_gemm<128, 32, true><<<CEILDIV(n, 32), 256, 0, stream>>>(abuf, W2, hbuf, n);
    k_aggregate<128><<<CEILDIV(n, 4), 256, 0, stream>>>(hbuf, rowstart, esrc, dinv, b2, abuf, n);

    // --- layer 3 (K=64) ---
    k_gemm<64, 64, true><<<CEILDIV(n, 64), 256, 0, stream>>>(abuf, W3, hbuf, n);
    k_aggregate<64><<<CEILDIV(n, 4), 256, 0, stream>>>(hbuf, rowstart, esrc, dinv, b3, out, n);
}

// Round 9
// 434.417 us; speedup vs baseline: 11.4293x; 1.2932x over previous
//
#include <hip/hip_runtime.h>

#define N_NODES 50000
#define N_EDGES 800000
#define CEILDIV(a,b) (((a)+(b)-1)/(b))
#define NB_SCAN CEILDIV(N_NODES, 256)   // 196 blocks

// ---------------------------------------------------------------------------
// CSR build (once per call, shared by all 3 layers)
// ---------------------------------------------------------------------------
__global__ __launch_bounds__(256) void k_deg_count(const int* __restrict__ dst,
                                                   int* __restrict__ degcnt, int e) {
    int i = blockIdx.x * 256 + threadIdx.x;
    if (i < e) atomicAdd(&degcnt[dst[i]], 1);
}

// phase 1: per-block sums of degcnt (coalesced)
__global__ __launch_bounds__(256) void k_blocksum(const int* __restrict__ degcnt,
                                                  int* __restrict__ bsum, int n) {
    __shared__ int part[256];
    const int tid = threadIdx.x;
    const int gid = blockIdx.x * 256 + tid;
    part[tid] = (gid < n) ? degcnt[gid] : 0;
    __syncthreads();
    for (int off = 128; off > 0; off >>= 1) {
        if (tid < off) part[tid] += part[tid + off];
        __syncthreads();
    }
    if (tid == 0) bsum[blockIdx.x] = part[0];
}

// phase 2: exclusive scan of the NB_SCAN block sums (one tiny block)
__global__ __launch_bounds__(256) void k_scanb(const int* __restrict__ bsum,
                                               int* __restrict__ boff) {
    __shared__ int part[256];
    const int tid = threadIdx.x;
    part[tid] = (tid < NB_SCAN) ? bsum[tid] : 0;
    __syncthreads();
    for (int off = 1; off < 256; off <<= 1) {
        int v = (tid >= off) ? part[tid - off] : 0;
        __syncthreads();
        part[tid] += v;
        __syncthreads();
    }
    if (tid < NB_SCAN) boff[tid] = (tid == 0) ? 0 : part[tid - 1];
}

// phase 3: in-block exclusive scan + block offset -> rowstart; also dinv
__global__ __launch_bounds__(256) void k_rowstart(const int* __restrict__ degcnt,
                                                  const int* __restrict__ boff,
                                                  int* __restrict__ rowstart,
                                                  float* __restrict__ dinv, int n) {
    __shared__ int part[256];
    const int tid = threadIdx.x;
    const int gid = blockIdx.x * 256 + tid;
    const int d = (gid < n) ? degcnt[gid] : 0;
    part[tid] = d;
    __syncthreads();
    for (int off = 1; off < 256; off <<= 1) {
        int v = (tid >= off) ? part[tid - off] : 0;
        __syncthreads();
        part[tid] += v;
        __syncthreads();
    }
    if (gid < n) {
        rowstart[gid] = boff[blockIdx.x] + part[tid] - d;   // exclusive
        dinv[gid] = rsqrtf((float)(d + 1));                 // +1 self loop
    }
    if (gid == 0) rowstart[n] = N_EDGES;                    // total degree = E
}

__global__ __launch_bounds__(256) void k_bin(const int* __restrict__ src,
                                             const int* __restrict__ dst,
                                             const int* __restrict__ rowstart,
                                             int* __restrict__ cursor,
                                             int* __restrict__ esrc, int e) {
    int i = blockIdx.x * 256 + threadIdx.x;
    if (i < e) {
        int d = dst[i];
        int pos = rowstart[d] + atomicAdd(&cursor[d], 1);
        esrc[pos] = src[i];
    }
}

// ---------------------------------------------------------------------------
// GEMM: C[n][K] = (RELU? relu(A) : A)[n][128] @ W[128][K]
// Static accumulator access + BOUNDED unroll (full unroll of the 32-iter
// K-loop made the scheduler hoist 256 ds_reads -> 256 VGPR + scratch spill).
// ---------------------------------------------------------------------------
template<int K, int ROWS, bool RELU>
__global__ __launch_bounds__(256) void k_gemm(const float* __restrict__ A,
                                              const float* __restrict__ W,
                                              float* __restrict__ C, int n) {
    constexpr int M  = 128;
    constexpr int CG = K / 4;      // float4 column groups
    __shared__ float4 Wl4[M * CG];
    __shared__ float4 Al4[ROWS * 32];

    const int tid  = threadIdx.x;
    const int row0 = blockIdx.x * ROWS;

    // stage W -> LDS
    constexpr int WV = (M * CG) / 256;
    const float4* W4 = (const float4*)W;
#pragma unroll
    for (int i = 0; i < WV; ++i) Wl4[tid + i * 256] = W4[tid + i * 256];

    // stage A tile -> LDS (fused ReLU; tail rows zeroed)
    constexpr int AV = (ROWS * 32) / 256;
#pragma unroll
    for (int i = 0; i < AV; ++i) {
        int f  = tid + i * 256;
        int r  = f >> 5;
        int gr = row0 + r;
        float4 v;
        if (gr < n) {
            v = ((const float4*)A)[(size_t)gr * 32 + (f & 31)];
            if (RELU) {
                v.x = fmaxf(v.x, 0.f); v.y = fmaxf(v.y, 0.f);
                v.z = fmaxf(v.z, 0.f); v.w = fmaxf(v.w, 0.f);
            }
        } else {
            v = make_float4(0.f, 0.f, 0.f, 0.f);
        }
        Al4[f] = v;
    }
    __syncthreads();

    const int cg = tid % CG;
    const int rg = tid / CG;

    float4 acc0 = make_float4(0.f, 0.f, 0.f, 0.f);
    float4 acc1 = acc0, acc2 = acc0, acc3 = acc0;

#pragma unroll 2
    for (int m4 = 0; m4 < 32; ++m4) {
        const float4 w0 = Wl4[(m4 * 4 + 0) * CG + cg];
        const float4 w1 = Wl4[(m4 * 4 + 1) * CG + cg];
        const float4 w2 = Wl4[(m4 * 4 + 2) * CG + cg];
        const float4 w3 = Wl4[(m4 * 4 + 3) * CG + cg];

#define ROW_STEP(AV_, ACC_)                                   \
        {                                                     \
            const float4 a_ = (AV_);                          \
            ACC_.x = fmaf(a_.x, w0.x, ACC_.x);                \
            ACC_.x = fmaf(a_.y, w1.x, ACC_.x);                \
            ACC_.x = fmaf(a_.z, w2.x, ACC_.x);                \
            ACC_.x = fmaf(a_.w, w3.x, ACC_.x);                \
            ACC_.y = fmaf(a_.x, w0.y, ACC_.y);                \
            ACC_.y = fmaf(a_.y, w1.y, ACC_.y);                \
            ACC_.y = fmaf(a_.z, w2.y, ACC_.y);                \
            ACC_.y = fmaf(a_.w, w3.y, ACC_.y);                \
            ACC_.z = fmaf(a_.x, w0.z, ACC_.z);                \
            ACC_.z = fmaf(a_.y, w1.z, ACC_.z);                \
            ACC_.z = fmaf(a_.z, w2.z, ACC_.z);                \
            ACC_.z = fmaf(a_.w, w3.z, ACC_.z);                \
            ACC_.w = fmaf(a_.x, w0.w, ACC_.w);                \
            ACC_.w = fmaf(a_.y, w1.w, ACC_.w);                \
            ACC_.w = fmaf(a_.z, w2.w, ACC_.w);                \
            ACC_.w = fmaf(a_.w, w3.w, ACC_.w);                \
        }

        ROW_STEP(Al4[(rg * 4 + 0) * 32 + m4], acc0);
        ROW_STEP(Al4[(rg * 4 + 1) * 32 + m4], acc1);
        ROW_STEP(Al4[(rg * 4 + 2) * 32 + m4], acc2);
        ROW_STEP(Al4[(rg * 4 + 3) * 32 + m4], acc3);
#undef ROW_STEP
    }

    {
        int gr = row0 + rg * 4;
        if (gr + 0 < n) ((float4*)C)[(size_t)(gr + 0) * CG + cg] = acc0;
        if (gr + 1 < n) ((float4*)C)[(size_t)(gr + 1) * CG + cg] = acc1;
        if (gr + 2 < n) ((float4*)C)[(size_t)(gr + 2) * CG + cg] = acc2;
        if (gr + 3 < n) ((float4*)C)[(size_t)(gr + 3) * CG + cg] = acc3;
    }
}

// ---------------------------------------------------------------------------
// Gather aggregation: one wave per destination node.
// ---------------------------------------------------------------------------
template<int K>
__global__ __launch_bounds__(256) void k_aggregate(const float* __restrict__ h,
                                                   const int* __restrict__ rowstart,
                                                   const int* __restrict__ esrc,
                                                   const float* __restrict__ dinv,
                                                   const float* __restrict__ b,
                                                   float* __restrict__ out, int n) {
    constexpr int VEC = K / 64;           // floats per lane
    const int wave = threadIdx.x >> 6;
    const int lane = threadIdx.x & 63;
    const int node = blockIdx.x * 4 + wave;
    if (node >= n) return;

    const float dd = dinv[node];

    float acc0, acc1;
    if (VEC == 2) {
        float2 hv = ((const float2*)h)[(size_t)node * 64 + lane];
        float2 bv = ((const float2*)b)[lane];
        acc0 = hv.x * dd * dd + bv.x;
        acc1 = hv.y * dd * dd + bv.y;
    } else {
        acc0 = h[(size_t)node * K + lane] * dd * dd + b[lane];
        acc1 = 0.f;
    }

    int row = rowstart[node];
    const int end = rowstart[node + 1];
    while (row < end) {
        int cnt = end - row;
        if (cnt > 64) cnt = 64;
        int   s_l  = (lane < cnt) ? esrc[row + lane] : 0;
        float nv_l = (lane < cnt) ? dinv[s_l] * dd : 0.f;
        for (int j = 0; j < cnt; ++j) {
            int   s   = __shfl(s_l, j);
            float nrm = __shfl(nv_l, j);
            if (VEC == 2) {
                float2 hv = ((const float2*)h)[(size_t)s * 64 + lane];
                acc0 += hv.x * nrm;
                acc1 += hv.y * nrm;
            } else {
                acc0 += h[(size_t)s * K + lane] * nrm;
            }
        }
        row += cnt;
    }

    if (VEC == 2) {
        ((float2*)out)[(size_t)node * 64 + lane] = make_float2(acc0, acc1);
    } else {
        out[(size_t)node * K + lane] = acc0;
    }
}

// ---------------------------------------------------------------------------
extern "C" void kernel_launch(void* const* d_in, const int* in_sizes, int n_in,
                              void* d_out, int out_size, void* d_ws, size_t ws_size,
                              hipStream_t stream) {
    const float* x  = (const float*)d_in[0];
    const int*   ei = (const int*)d_in[1];
    const float* W1 = (const float*)d_in[2];
    const float* b1 = (const float*)d_in[3];
    const float* W2 = (const float*)d_in[4];
    const float* b2 = (const float*)d_in[5];
    const float* W3 = (const float*)d_in[6];
    const float* b3 = (const float*)d_in[7];
    float* out = (float*)d_out;

    const int* src = ei;
    const int* dst = ei + N_EDGES;

    char* ws = (char*)d_ws;
    size_t off = 0;
    auto alloc = [&](size_t bytes) {
        void* p = ws + off;
        off += (bytes + 255) & ~(size_t)255;
        return p;
    };
    int*   degcnt   = (int*)alloc(N_NODES * 4);
    int*   cursor   = (int*)alloc(N_NODES * 4);
    int*   rowstart = (int*)alloc((N_NODES + 1) * 4);
    float* dinv     = (float*)alloc(N_NODES * 4);
    int*   bsum     = (int*)alloc(NB_SCAN * 4);
    int*   boff     = (int*)alloc(NB_SCAN * 4);
    int*   esrc     = (int*)alloc((size_t)N_EDGES * 4);
    float* hbuf     = (float*)alloc((size_t)N_NODES * 128 * 4);
    float* abuf     = (float*)alloc((size_t)N_NODES * 128 * 4);

    const int n = N_NODES, e = N_EDGES;

    // --- CSR build (once; reused by all layers) ---
    hipMemsetAsync(degcnt, 0, N_NODES * 4, stream);
    hipMemsetAsync(cursor, 0, N_NODES * 4, stream);
    k_deg_count<<<CEILDIV(e, 256), 256, 0, stream>>>(dst, degcnt, e);
    k_blocksum<<<NB_SCAN, 256, 0, stream>>>(degcnt, bsum, n);
    k_scanb<<<1, 256, 0, stream>>>(bsum, boff);
    k_rowstart<<<NB_SCAN, 256, 0, stream>>>(degcnt, boff, rowstart, dinv, n);
    k_bin<<<CEILDIV(e, 256), 256, 0, stream>>>(src, dst, rowstart, cursor, esrc, e);

    // --- layer 1 ---
    k_gemm<128, 32, false><<<CEILDIV(n, 32), 256, 0, stream>>>(x, W1, hbuf, n);
    k_aggregate<128><<<CEILDIV(n, 4), 256, 0, stream>>>(hbuf, rowstart, esrc, dinv, b1, abuf, n);

    // --- layer 2 ---
    k_gemm<128, 32, true><<<CEILDIV(n, 32), 256, 0, stream>>>(abuf, W2, hbuf, n);
    k_aggregate<128><<<CEILDIV(n, 4), 256, 0, stream>>>(hbuf, rowstart, esrc, dinv, b2, abuf, n);

    // --- layer 3 (K=64) ---
    k_gemm<64, 64, true><<<CEILDIV(n, 64), 256, 0, stream>>>(abuf, W3, hbuf, n);
    k_aggregate<64><<<CEILDIV(n, 4), 256, 0, stream>>>(hbuf, rowstart, esrc, dinv, b3, out, n);
}

// Round 10
// 426.287 us; speedup vs baseline: 11.6473x; 1.0191x over previous
//
#include <hip/hip_runtime.h>

#define N_NODES 50000
#define N_EDGES 800000
#define CEILDIV(a,b) (((a)+(b)-1)/(b))
#define NB_SCAN CEILDIV(N_NODES, 256)   // 196 blocks

// ---------------------------------------------------------------------------
// CSR build (once per call, shared by all 3 layers)
// ---------------------------------------------------------------------------
__global__ __launch_bounds__(256) void k_deg_count(const int* __restrict__ dst,
                                                   int* __restrict__ degcnt, int e) {
    int i = blockIdx.x * 256 + threadIdx.x;
    if (i < e) atomicAdd(&degcnt[dst[i]], 1);
}

__global__ __launch_bounds__(256) void k_blocksum(const int* __restrict__ degcnt,
                                                  int* __restrict__ bsum, int n) {
    __shared__ int part[256];
    const int tid = threadIdx.x;
    const int gid = blockIdx.x * 256 + tid;
    part[tid] = (gid < n) ? degcnt[gid] : 0;
    __syncthreads();
    for (int off = 128; off > 0; off >>= 1) {
        if (tid < off) part[tid] += part[tid + off];
        __syncthreads();
    }
    if (tid == 0) bsum[blockIdx.x] = part[0];
}

__global__ __launch_bounds__(256) void k_scanb(const int* __restrict__ bsum,
                                               int* __restrict__ boff) {
    __shared__ int part[256];
    const int tid = threadIdx.x;
    part[tid] = (tid < NB_SCAN) ? bsum[tid] : 0;
    __syncthreads();
    for (int off = 1; off < 256; off <<= 1) {
        int v = (tid >= off) ? part[tid - off] : 0;
        __syncthreads();
        part[tid] += v;
        __syncthreads();
    }
    if (tid < NB_SCAN) boff[tid] = (tid == 0) ? 0 : part[tid - 1];
}

__global__ __launch_bounds__(256) void k_rowstart(const int* __restrict__ degcnt,
                                                  const int* __restrict__ boff,
                                                  int* __restrict__ rowstart,
                                                  float* __restrict__ dinv, int n) {
    __shared__ int part[256];
    const int tid = threadIdx.x;
    const int gid = blockIdx.x * 256 + tid;
    const int d = (gid < n) ? degcnt[gid] : 0;
    part[tid] = d;
    __syncthreads();
    for (int off = 1; off < 256; off <<= 1) {
        int v = (tid >= off) ? part[tid - off] : 0;
        __syncthreads();
        part[tid] += v;
        __syncthreads();
    }
    if (gid < n) {
        rowstart[gid] = boff[blockIdx.x] + part[tid] - d;   // exclusive
        dinv[gid] = rsqrtf((float)(d + 1));                 // +1 self loop
    }
    if (gid == 0) rowstart[n] = N_EDGES;
}

__global__ __launch_bounds__(256) void k_bin(const int* __restrict__ src,
                                             const int* __restrict__ dst,
                                             const int* __restrict__ rowstart,
                                             int* __restrict__ cursor,
                                             int* __restrict__ esrc, int e) {
    int i = blockIdx.x * 256 + threadIdx.x;
    if (i < e) {
        int d = dst[i];
        int pos = rowstart[d] + atomicAdd(&cursor[d], 1);
        esrc[pos] = src[i];
    }
}

// ---------------------------------------------------------------------------
// GEMM + row-scale: C[i][:] = ((RELU? relu(A):A)[i] @ W) * dinv[i]
// W in LDS (64/32 KB). A read DIRECTLY from global: the 32 threads sharing a
// row issue the same address -> one transaction + L1 broadcast; removes the
// A-tile ds_reads (old kernel was LDS-pipe-bound: 8 ds_read_b128/64 FMA).
// ---------------------------------------------------------------------------
template<int K, bool RELU>
__global__ __launch_bounds__(256) void k_gemm(const float* __restrict__ A,
                                              const float* __restrict__ W,
                                              const float* __restrict__ dinv,
                                              float* __restrict__ C, int n) {
    constexpr int CG   = K / 4;            // float4 col groups (32 or 16)
    constexpr int RG   = 256 / CG;         // row groups per block (8 or 16)
    constexpr int ROWS = RG * 4;           // rows per block (32 or 64)
    __shared__ float4 Wl4[128 * CG];

    const int tid  = threadIdx.x;
    const int row0 = blockIdx.x * ROWS;

    constexpr int WV = (128 * CG) / 256;
    const float4* W4 = (const float4*)W;
#pragma unroll
    for (int i = 0; i < WV; ++i) Wl4[tid + i * 256] = W4[tid + i * 256];
    __syncthreads();

    const int cg = tid % CG;
    const int rg = tid / CG;
    const int gr = row0 + rg * 4;

    // clamped row pointers (tail block): garbage rows computed, not stored
    const float4* p0 = (const float4*)A + (size_t)min(gr + 0, n - 1) * 32;
    const float4* p1 = (const float4*)A + (size_t)min(gr + 1, n - 1) * 32;
    const float4* p2 = (const float4*)A + (size_t)min(gr + 2, n - 1) * 32;
    const float4* p3 = (const float4*)A + (size_t)min(gr + 3, n - 1) * 32;

    float4 acc0 = make_float4(0.f, 0.f, 0.f, 0.f);
    float4 acc1 = acc0, acc2 = acc0, acc3 = acc0;

#pragma unroll 2
    for (int m4 = 0; m4 < 32; ++m4) {
        float4 a0 = p0[m4], a1 = p1[m4], a2 = p2[m4], a3 = p3[m4];
        if (RELU) {
            a0.x = fmaxf(a0.x, 0.f); a0.y = fmaxf(a0.y, 0.f); a0.z = fmaxf(a0.z, 0.f); a0.w = fmaxf(a0.w, 0.f);
            a1.x = fmaxf(a1.x, 0.f); a1.y = fmaxf(a1.y, 0.f); a1.z = fmaxf(a1.z, 0.f); a1.w = fmaxf(a1.w, 0.f);
            a2.x = fmaxf(a2.x, 0.f); a2.y = fmaxf(a2.y, 0.f); a2.z = fmaxf(a2.z, 0.f); a2.w = fmaxf(a2.w, 0.f);
            a3.x = fmaxf(a3.x, 0.f); a3.y = fmaxf(a3.y, 0.f); a3.z = fmaxf(a3.z, 0.f); a3.w = fmaxf(a3.w, 0.f);
        }
        const float4 w0 = Wl4[(m4 * 4 + 0) * CG + cg];
        const float4 w1 = Wl4[(m4 * 4 + 1) * CG + cg];
        const float4 w2 = Wl4[(m4 * 4 + 2) * CG + cg];
        const float4 w3 = Wl4[(m4 * 4 + 3) * CG + cg];

#define ROW_STEP(A_, ACC_)                                    \
        {                                                     \
            ACC_.x = fmaf(A_.x, w0.x, ACC_.x);                \
            ACC_.x = fmaf(A_.y, w1.x, ACC_.x);                \
            ACC_.x = fmaf(A_.z, w2.x, ACC_.x);                \
            ACC_.x = fmaf(A_.w, w3.x, ACC_.x);                \
            ACC_.y = fmaf(A_.x, w0.y, ACC_.y);                \
            ACC_.y = fmaf(A_.y, w1.y, ACC_.y);                \
            ACC_.y = fmaf(A_.z, w2.y, ACC_.y);                \
            ACC_.y = fmaf(A_.w, w3.y, ACC_.y);                \
            ACC_.z = fmaf(A_.x, w0.z, ACC_.z);                \
            ACC_.z = fmaf(A_.y, w1.z, ACC_.z);                \
            ACC_.z = fmaf(A_.z, w2.z, ACC_.z);                \
            ACC_.z = fmaf(A_.w, w3.z, ACC_.z);                \
            ACC_.w = fmaf(A_.x, w0.w, ACC_.w);                \
            ACC_.w = fmaf(A_.y, w1.w, ACC_.w);                \
            ACC_.w = fmaf(A_.z, w2.w, ACC_.w);                \
            ACC_.w = fmaf(A_.w, w3.w, ACC_.w);                \
        }
        ROW_STEP(a0, acc0);
        ROW_STEP(a1, acc1);
        ROW_STEP(a2, acc2);
        ROW_STEP(a3, acc3);
#undef ROW_STEP
    }

    // epilogue: scale each output row by dinv[row]  (h' = h * dinv)
    {
        float d0 = dinv[min(gr + 0, n - 1)];
        float d1 = dinv[min(gr + 1, n - 1)];
        float d2 = dinv[min(gr + 2, n - 1)];
        float d3 = dinv[min(gr + 3, n - 1)];
        acc0.x *= d0; acc0.y *= d0; acc0.z *= d0; acc0.w *= d0;
        acc1.x *= d1; acc1.y *= d1; acc1.z *= d1; acc1.w *= d1;
        acc2.x *= d2; acc2.y *= d2; acc2.z *= d2; acc2.w *= d2;
        acc3.x *= d3; acc3.y *= d3; acc3.z *= d3; acc3.w *= d3;
        if (gr + 0 < n) ((float4*)C)[(size_t)(gr + 0) * CG + cg] = acc0;
        if (gr + 1 < n) ((float4*)C)[(size_t)(gr + 1) * CG + cg] = acc1;
        if (gr + 2 < n) ((float4*)C)[(size_t)(gr + 2) * CG + cg] = acc2;
        if (gr + 3 < n) ((float4*)C)[(size_t)(gr + 3) * CG + cg] = acc3;
    }
}

// ---------------------------------------------------------------------------
// Gather aggregation v2 (pre-scaled h'):
//   out[d][:] = dinv[d] * ( h'[d][:] + sum_{e: dst=d} h'[src_e][:] ) + b
// One wave per node; DUAL-EDGE: lanes 0-31 even edges, 32-63 odd edges,
// each lane owns VEC cols. Combine halves with one shfl_xor(32) at the end.
// ---------------------------------------------------------------------------
template<int K>
__global__ __launch_bounds__(256) void k_aggregate(const float* __restrict__ h,
                                                   const int* __restrict__ rowstart,
                                                   const int* __restrict__ esrc,
                                                   const float* __restrict__ dinv,
                                                   const float* __restrict__ b,
                                                   float* __restrict__ out, int n) {
    constexpr int VEC = K / 32;            // floats per lane (4 or 2)
    const int wave = threadIdx.x >> 6;
    const int lane = threadIdx.x & 63;
    const int half = lane >> 5;            // 0: even edges, 1: odd edges
    const int l5   = lane & 31;            // col group
    const int node = blockIdx.x * 4 + wave;
    if (node >= n) return;

    float a0 = 0.f, a1 = 0.f, a2 = 0.f, a3 = 0.f;
    if (half == 0) {                        // self-loop term: h'[node]
        if (VEC == 4) {
            float4 v = ((const float4*)h)[(size_t)node * 32 + l5];
            a0 = v.x; a1 = v.y; a2 = v.z; a3 = v.w;
        } else {
            float2 v = ((const float2*)h)[(size_t)node * 32 + l5];
            a0 = v.x; a1 = v.y;
        }
    }

    int row = rowstart[node];
    const int end = rowstart[node + 1];
    while (row < end) {
        int cnt = end - row;
        if (cnt > 64) cnt = 64;
        int s_l = (lane < cnt) ? esrc[row + lane] : 0;
        const int steps = (cnt + 1) >> 1;
        for (int jj = 0; jj < steps; ++jj) {
            int idx = 2 * jj + half;
            int s = __shfl(s_l, idx);
            if (idx < cnt) {
                if (VEC == 4) {
                    float4 v = ((const float4*)h)[(size_t)s * 32 + l5];
                    a0 += v.x; a1 += v.y; a2 += v.z; a3 += v.w;
                } else {
                    float2 v = ((const float2*)h)[(size_t)s * 32 + l5];
                    a0 += v.x; a1 += v.y;
                }
            }
        }
        row += cnt;
    }

    // combine even/odd halves (lane l <-> lane l^32 hold the same cols)
    a0 += __shfl_xor(a0, 32);
    a1 += __shfl_xor(a1, 32);
    if (VEC == 4) {
        a2 += __shfl_xor(a2, 32);
        a3 += __shfl_xor(a3, 32);
    }

    if (half == 0) {
        const float dd = dinv[node];
        if (VEC == 4) {
            float4 bb = ((const float4*)b)[l5];
            float4 o;
            o.x = a0 * dd + bb.x;
            o.y = a1 * dd + bb.y;
            o.z = a2 * dd + bb.z;
            o.w = a3 * dd + bb.w;
            ((float4*)out)[(size_t)node * 32 + l5] = o;
        } else {
            float2 bb = ((const float2*)b)[l5];
            float2 o;
            o.x = a0 * dd + bb.x;
            o.y = a1 * dd + bb.y;
            ((float2*)out)[(size_t)node * 32 + l5] = o;
        }
    }
}

// ---------------------------------------------------------------------------
extern "C" void kernel_launch(void* const* d_in, const int* in_sizes, int n_in,
                              void* d_out, int out_size, void* d_ws, size_t ws_size,
                              hipStream_t stream) {
    const float* x  = (const float*)d_in[0];
    const int*   ei = (const int*)d_in[1];
    const float* W1 = (const float*)d_in[2];
    const float* b1 = (const float*)d_in[3];
    const float* W2 = (const float*)d_in[4];
    const float* b2 = (const float*)d_in[5];
    const float* W3 = (const float*)d_in[6];
    const float* b3 = (const float*)d_in[7];
    float* out = (float*)d_out;

    const int* src = ei;
    const int* dst = ei + N_EDGES;

    char* ws = (char*)d_ws;
    size_t off = 0;
    auto alloc = [&](size_t bytes) {
        void* p = ws + off;
        off += (bytes + 255) & ~(size_t)255;
        return p;
    };
    int*   degcnt   = (int*)alloc((size_t)N_NODES * 2 * 4);  // degcnt + cursor contiguous
    int*   cursor   = degcnt + N_NODES;
    int*   rowstart = (int*)alloc((N_NODES + 1) * 4);
    float* dinv     = (float*)alloc(N_NODES * 4);
    int*   bsum     = (int*)alloc(NB_SCAN * 4);
    int*   boff     = (int*)alloc(NB_SCAN * 4);
    int*   esrc     = (int*)alloc((size_t)N_EDGES * 4);
    float* hbuf     = (float*)alloc((size_t)N_NODES * 128 * 4);
    float* abuf     = (float*)alloc((size_t)N_NODES * 128 * 4);

    const int n = N_NODES, e = N_EDGES;

    // --- CSR build (once; reused by all layers) ---
    hipMemsetAsync(degcnt, 0, (size_t)N_NODES * 2 * 4, stream);
    k_deg_count<<<CEILDIV(e, 256), 256, 0, stream>>>(dst, degcnt, e);
    k_blocksum<<<NB_SCAN, 256, 0, stream>>>(degcnt, bsum, n);
    k_scanb<<<1, 256, 0, stream>>>(bsum, boff);
    k_rowstart<<<NB_SCAN, 256, 0, stream>>>(degcnt, boff, rowstart, dinv, n);
    k_bin<<<CEILDIV(e, 256), 256, 0, stream>>>(src, dst, rowstart, cursor, esrc, e);

    // --- layer 1 ---
    k_gemm<128, false><<<CEILDIV(n, 32), 256, 0, stream>>>(x, W1, dinv, hbuf, n);
    k_aggregate<128><<<CEILDIV(n, 4), 256, 0, stream>>>(hbuf, rowstart, esrc, dinv, b1, abuf, n);

    // --- layer 2 ---
    k_gemm<128, true><<<CEILDIV(n, 32), 256, 0, stream>>>(abuf, W2, dinv, hbuf, n);
    k_aggregate<128><<<CEILDIV(n, 4), 256, 0, stream>>>(hbuf, rowstart, esrc, dinv, b2, abuf, n);

    // --- layer 3 (K=64) ---
    k_gemm<64, true><<<CEILDIV(n, 64), 256, 0, stream>>>(abuf, W3, dinv, hbuf, n);
    k_aggregate<64><<<CEILDIV(n, 4), 256, 0, stream>>>(hbuf, rowstart, esrc, dinv, b3, out, n);
}

// Round 11
// 418.328 us; speedup vs baseline: 11.8689x; 1.0190x over previous
//
#include <hip/hip_runtime.h>

#define N_NODES 50000
#define N_EDGES 800000
#define CEILDIV(a,b) (((a)+(b)-1)/(b))
#define NB_SCAN CEILDIV(N_NODES, 256)   // 196 blocks

// ---------------------------------------------------------------------------
// CSR build (once per call, shared by all 3 layers)
// ---------------------------------------------------------------------------
__global__ __launch_bounds__(256) void k_deg_count(const int* __restrict__ dst,
                                                   int* __restrict__ degcnt, int e) {
    int i = blockIdx.x * 256 + threadIdx.x;
    if (i < e) atomicAdd(&degcnt[dst[i]], 1);
}

__global__ __launch_bounds__(256) void k_blocksum(const int* __restrict__ degcnt,
                                                  int* __restrict__ bsum, int n) {
    __shared__ int part[256];
    const int tid = threadIdx.x;
    const int gid = blockIdx.x * 256 + tid;
    part[tid] = (gid < n) ? degcnt[gid] : 0;
    __syncthreads();
    for (int off = 128; off > 0; off >>= 1) {
        if (tid < off) part[tid] += part[tid + off];
        __syncthreads();
    }
    if (tid == 0) bsum[blockIdx.x] = part[0];
}

__global__ __launch_bounds__(256) void k_scanb(const int* __restrict__ bsum,
                                               int* __restrict__ boff) {
    __shared__ int part[256];
    const int tid = threadIdx.x;
    part[tid] = (tid < NB_SCAN) ? bsum[tid] : 0;
    __syncthreads();
    for (int off = 1; off < 256; off <<= 1) {
        int v = (tid >= off) ? part[tid - off] : 0;
        __syncthreads();
        part[tid] += v;
        __syncthreads();
    }
    if (tid < NB_SCAN) boff[tid] = (tid == 0) ? 0 : part[tid - 1];
}

__global__ __launch_bounds__(256) void k_rowstart(const int* __restrict__ degcnt,
                                                  const int* __restrict__ boff,
                                                  int* __restrict__ rowstart,
                                                  float* __restrict__ dinv, int n) {
    __shared__ int part[256];
    const int tid = threadIdx.x;
    const int gid = blockIdx.x * 256 + tid;
    const int d = (gid < n) ? degcnt[gid] : 0;
    part[tid] = d;
    __syncthreads();
    for (int off = 1; off < 256; off <<= 1) {
        int v = (tid >= off) ? part[tid - off] : 0;
        __syncthreads();
        part[tid] += v;
        __syncthreads();
    }
    if (gid < n) {
        rowstart[gid] = boff[blockIdx.x] + part[tid] - d;   // exclusive
        dinv[gid] = rsqrtf((float)(d + 1));                 // +1 self loop
    }
    if (gid == 0) rowstart[n] = N_EDGES;
}

__global__ __launch_bounds__(256) void k_bin(const int* __restrict__ src,
                                             const int* __restrict__ dst,
                                             const int* __restrict__ rowstart,
                                             int* __restrict__ cursor,
                                             int* __restrict__ esrc, int e) {
    int i = blockIdx.x * 256 + threadIdx.x;
    if (i < e) {
        int d = dst[i];
        int pos = rowstart[d] + atomicAdd(&cursor[d], 1);
        esrc[pos] = src[i];
    }
}

// ---------------------------------------------------------------------------
// GEMM + row-scale: C[i][:] = ((RELU? relu(A):A)[i] @ W) * dinv[i]
// W in LDS; A read directly from global (row broadcast via L1).
// ---------------------------------------------------------------------------
template<int K, bool RELU>
__global__ __launch_bounds__(256) void k_gemm(const float* __restrict__ A,
                                              const float* __restrict__ W,
                                              const float* __restrict__ dinv,
                                              float* __restrict__ C, int n) {
    constexpr int CG   = K / 4;            // float4 col groups (32 or 16)
    constexpr int RG   = 256 / CG;         // row groups per block (8 or 16)
    constexpr int ROWS = RG * 4;           // rows per block (32 or 64)
    __shared__ float4 Wl4[128 * CG];

    const int tid  = threadIdx.x;
    const int row0 = blockIdx.x * ROWS;

    constexpr int WV = (128 * CG) / 256;
    const float4* W4 = (const float4*)W;
#pragma unroll
    for (int i = 0; i < WV; ++i) Wl4[tid + i * 256] = W4[tid + i * 256];
    __syncthreads();

    const int cg = tid % CG;
    const int rg = tid / CG;
    const int gr = row0 + rg * 4;

    const float4* p0 = (const float4*)A + (size_t)min(gr + 0, n - 1) * 32;
    const float4* p1 = (const float4*)A + (size_t)min(gr + 1, n - 1) * 32;
    const float4* p2 = (const float4*)A + (size_t)min(gr + 2, n - 1) * 32;
    const float4* p3 = (const float4*)A + (size_t)min(gr + 3, n - 1) * 32;

    float4 acc0 = make_float4(0.f, 0.f, 0.f, 0.f);
    float4 acc1 = acc0, acc2 = acc0, acc3 = acc0;

#pragma unroll 2
    for (int m4 = 0; m4 < 32; ++m4) {
        float4 a0 = p0[m4], a1 = p1[m4], a2 = p2[m4], a3 = p3[m4];
        if (RELU) {
            a0.x = fmaxf(a0.x, 0.f); a0.y = fmaxf(a0.y, 0.f); a0.z = fmaxf(a0.z, 0.f); a0.w = fmaxf(a0.w, 0.f);
            a1.x = fmaxf(a1.x, 0.f); a1.y = fmaxf(a1.y, 0.f); a1.z = fmaxf(a1.z, 0.f); a1.w = fmaxf(a1.w, 0.f);
            a2.x = fmaxf(a2.x, 0.f); a2.y = fmaxf(a2.y, 0.f); a2.z = fmaxf(a2.z, 0.f); a2.w = fmaxf(a2.w, 0.f);
            a3.x = fmaxf(a3.x, 0.f); a3.y = fmaxf(a3.y, 0.f); a3.z = fmaxf(a3.z, 0.f); a3.w = fmaxf(a3.w, 0.f);
        }
        const float4 w0 = Wl4[(m4 * 4 + 0) * CG + cg];
        const float4 w1 = Wl4[(m4 * 4 + 1) * CG + cg];
        const float4 w2 = Wl4[(m4 * 4 + 2) * CG + cg];
        const float4 w3 = Wl4[(m4 * 4 + 3) * CG + cg];

#define ROW_STEP(A_, ACC_)                                    \
        {                                                     \
            ACC_.x = fmaf(A_.x, w0.x, ACC_.x);                \
            ACC_.x = fmaf(A_.y, w1.x, ACC_.x);                \
            ACC_.x = fmaf(A_.z, w2.x, ACC_.x);                \
            ACC_.x = fmaf(A_.w, w3.x, ACC_.x);                \
            ACC_.y = fmaf(A_.x, w0.y, ACC_.y);                \
            ACC_.y = fmaf(A_.y, w1.y, ACC_.y);                \
            ACC_.y = fmaf(A_.z, w2.y, ACC_.y);                \
            ACC_.y = fmaf(A_.w, w3.y, ACC_.y);                \
            ACC_.z = fmaf(A_.x, w0.z, ACC_.z);                \
            ACC_.z = fmaf(A_.y, w1.z, ACC_.z);                \
            ACC_.z = fmaf(A_.z, w2.z, ACC_.z);                \
            ACC_.z = fmaf(A_.w, w3.z, ACC_.z);                \
            ACC_.w = fmaf(A_.x, w0.w, ACC_.w);                \
            ACC_.w = fmaf(A_.y, w1.w, ACC_.w);                \
            ACC_.w = fmaf(A_.z, w2.w, ACC_.w);                \
            ACC_.w = fmaf(A_.w, w3.w, ACC_.w);                \
        }
        ROW_STEP(a0, acc0);
        ROW_STEP(a1, acc1);
        ROW_STEP(a2, acc2);
        ROW_STEP(a3, acc3);
#undef ROW_STEP
    }

    {
        float d0 = dinv[min(gr + 0, n - 1)];
        float d1 = dinv[min(gr + 1, n - 1)];
        float d2 = dinv[min(gr + 2, n - 1)];
        float d3 = dinv[min(gr + 3, n - 1)];
        acc0.x *= d0; acc0.y *= d0; acc0.z *= d0; acc0.w *= d0;
        acc1.x *= d1; acc1.y *= d1; acc1.z *= d1; acc1.w *= d1;
        acc2.x *= d2; acc2.y *= d2; acc2.z *= d2; acc2.w *= d2;
        acc3.x *= d3; acc3.y *= d3; acc3.z *= d3; acc3.w *= d3;
        if (gr + 0 < n) ((float4*)C)[(size_t)(gr + 0) * CG + cg] = acc0;
        if (gr + 1 < n) ((float4*)C)[(size_t)(gr + 1) * CG + cg] = acc1;
        if (gr + 2 < n) ((float4*)C)[(size_t)(gr + 2) * CG + cg] = acc2;
        if (gr + 3 < n) ((float4*)C)[(size_t)(gr + 3) * CG + cg] = acc3;
    }
}

// ---------------------------------------------------------------------------
// Gather aggregation v3 (pre-scaled h', dual-edge, 4-STEP BATCHED LOADS):
//   out[d][:] = dinv[d] * ( h'[d][:] + sum_{e: dst=d} h'[src_e][:] ) + b
// The batched loads give 4 independent gathers in flight per wave (8 rows
// counting the two halves) instead of 1 -> hides L2/HBM latency.
// ---------------------------------------------------------------------------
template<int K>
__global__ __launch_bounds__(256) void k_aggregate(const float* __restrict__ h,
                                                   const int* __restrict__ rowstart,
                                                   const int* __restrict__ esrc,
                                                   const float* __restrict__ dinv,
                                                   const float* __restrict__ b,
                                                   float* __restrict__ out, int n) {
    constexpr int VEC = K / 32;            // floats per lane (4 or 2)
    const int wave = threadIdx.x >> 6;
    const int lane = threadIdx.x & 63;
    const int half = lane >> 5;            // 0: even edges, 1: odd edges
    const int l5   = lane & 31;            // col group
    const int node = blockIdx.x * 4 + wave;
    if (node >= n) return;

    float a0 = 0.f, a1 = 0.f, a2 = 0.f, a3 = 0.f;
    if (half == 0) {                        // self-loop term: h'[node]
        if (VEC == 4) {
            float4 v = ((const float4*)h)[(size_t)node * 32 + l5];
            a0 = v.x; a1 = v.y; a2 = v.z; a3 = v.w;
        } else {
            float2 v = ((const float2*)h)[(size_t)node * 32 + l5];
            a0 = v.x; a1 = v.y;
        }
    }

    int row = rowstart[node];
    const int end = rowstart[node + 1];
    while (row < end) {
        int cnt = end - row;
        if (cnt > 64) cnt = 64;
        int s_l = (lane < cnt) ? esrc[row + lane] : 0;
        const int steps = (cnt + 1) >> 1;
        // 4-step batches: 4 independent loads in flight per wave
        for (int jj = 0; jj < steps; jj += 4) {
            const int i0 = 2 * (jj + 0) + half;
            const int i1 = 2 * (jj + 1) + half;
            const int i2 = 2 * (jj + 2) + half;
            const int i3 = 2 * (jj + 3) + half;
            const int s0 = __shfl(s_l, i0);
            const int s1 = __shfl(s_l, i1);
            const int s2 = __shfl(s_l, i2);
            const int s3 = __shfl(s_l, i3);
            if (VEC == 4) {
                float4 v0 = make_float4(0.f,0.f,0.f,0.f), v1 = v0, v2 = v0, v3 = v0;
                if (i0 < cnt) v0 = ((const float4*)h)[(size_t)s0 * 32 + l5];
                if (i1 < cnt) v1 = ((const float4*)h)[(size_t)s1 * 32 + l5];
                if (i2 < cnt) v2 = ((const float4*)h)[(size_t)s2 * 32 + l5];
                if (i3 < cnt) v3 = ((const float4*)h)[(size_t)s3 * 32 + l5];
                a0 += (v0.x + v1.x) + (v2.x + v3.x);
                a1 += (v0.y + v1.y) + (v2.y + v3.y);
                a2 += (v0.z + v1.z) + (v2.z + v3.z);
                a3 += (v0.w + v1.w) + (v2.w + v3.w);
            } else {
                float2 v0 = make_float2(0.f,0.f), v1 = v0, v2 = v0, v3 = v0;
                if (i0 < cnt) v0 = ((const float2*)h)[(size_t)s0 * 32 + l5];
                if (i1 < cnt) v1 = ((const float2*)h)[(size_t)s1 * 32 + l5];
                if (i2 < cnt) v2 = ((const float2*)h)[(size_t)s2 * 32 + l5];
                if (i3 < cnt) v3 = ((const float2*)h)[(size_t)s3 * 32 + l5];
                a0 += (v0.x + v1.x) + (v2.x + v3.x);
                a1 += (v0.y + v1.y) + (v2.y + v3.y);
            }
        }
        row += cnt;
    }

    // combine even/odd halves (lane l <-> lane l^32 hold the same cols)
    a0 += __shfl_xor(a0, 32);
    a1 += __shfl_xor(a1, 32);
    if (VEC == 4) {
        a2 += __shfl_xor(a2, 32);
        a3 += __shfl_xor(a3, 32);
    }

    if (half == 0) {
        const float dd = dinv[node];
        if (VEC == 4) {
            float4 bb = ((const float4*)b)[l5];
            float4 o;
            o.x = a0 * dd + bb.x;
            o.y = a1 * dd + bb.y;
            o.z = a2 * dd + bb.z;
            o.w = a3 * dd + bb.w;
            ((float4*)out)[(size_t)node * 32 + l5] = o;
        } else {
            float2 bb = ((const float2*)b)[l5];
            float2 o;
            o.x = a0 * dd + bb.x;
            o.y = a1 * dd + bb.y;
            ((float2*)out)[(size_t)node * 32 + l5] = o;
        }
    }
}

// ---------------------------------------------------------------------------
extern "C" void kernel_launch(void* const* d_in, const int* in_sizes, int n_in,
                              void* d_out, int out_size, void* d_ws, size_t ws_size,
                              hipStream_t stream) {
    const float* x  = (const float*)d_in[0];
    const int*   ei = (const int*)d_in[1];
    const float* W1 = (const float*)d_in[2];
    const float* b1 = (const float*)d_in[3];
    const float* W2 = (const float*)d_in[4];
    const float* b2 = (const float*)d_in[5];
    const float* W3 = (const float*)d_in[6];
    const float* b3 = (const float*)d_in[7];
    float* out = (float*)d_out;

    const int* src = ei;
    const int* dst = ei + N_EDGES;

    char* ws = (char*)d_ws;
    size_t off = 0;
    auto alloc = [&](size_t bytes) {
        void* p = ws + off;
        off += (bytes + 255) & ~(size_t)255;
        return p;
    };
    int*   degcnt   = (int*)alloc((size_t)N_NODES * 2 * 4);  // degcnt + cursor contiguous
    int*   cursor   = degcnt + N_NODES;
    int*   rowstart = (int*)alloc((N_NODES + 1) * 4);
    float* dinv     = (float*)alloc(N_NODES * 4);
    int*   bsum     = (int*)alloc(NB_SCAN * 4);
    int*   boff     = (int*)alloc(NB_SCAN * 4);
    int*   esrc     = (int*)alloc((size_t)N_EDGES * 4);
    float* hbuf     = (float*)alloc((size_t)N_NODES * 128 * 4);
    float* abuf     = (float*)alloc((size_t)N_NODES * 128 * 4);

    const int n = N_NODES, e = N_EDGES;

    // --- CSR build (once; reused by all layers) ---
    hipMemsetAsync(degcnt, 0, (size_t)N_NODES * 2 * 4, stream);
    k_deg_count<<<CEILDIV(e, 256), 256, 0, stream>>>(dst, degcnt, e);
    k_blocksum<<<NB_SCAN, 256, 0, stream>>>(degcnt, bsum, n);
    k_scanb<<<1, 256, 0, stream>>>(bsum, boff);
    k_rowstart<<<NB_SCAN, 256, 0, stream>>>(degcnt, boff, rowstart, dinv, n);
    k_bin<<<CEILDIV(e, 256), 256, 0, stream>>>(src, dst, rowstart, cursor, esrc, e);

    // --- layer 1 ---
    k_gemm<128, false><<<CEILDIV(n, 32), 256, 0, stream>>>(x, W1, dinv, hbuf, n);
    k_aggregate<128><<<CEILDIV(n, 4), 256, 0, stream>>>(hbuf, rowstart, esrc, dinv, b1, abuf, n);

    // --- layer 2 ---
    k_gemm<128, true><<<CEILDIV(n, 32), 256, 0, stream>>>(abuf, W2, dinv, hbuf, n);
    k_aggregate<128><<<CEILDIV(n, 4), 256, 0, stream>>>(hbuf, rowstart, esrc, dinv, b2, abuf, n);

    // --- layer 3 (K=64) ---
    k_gemm<64, true><<<CEILDIV(n, 64), 256, 0, stream>>>(abuf, W3, dinv, hbuf, n);
    k_aggregate<64><<<CEILDIV(n, 4), 256, 0, stream>>>(hbuf, rowstart, esrc, dinv, b3, out, n);
}

// Round 12
// 344.894 us; speedup vs baseline: 14.3960x; 1.2129x over previous
//
#include <hip/hip_runtime.h>
#include <hip/hip_fp16.h>

#define N_NODES 50000
#define N_EDGES 800000
#define CEILDIV(a,b) (((a)+(b)-1)/(b))
#define NB_SCAN CEILDIV(N_NODES, 256)   // 196 blocks

// ---------------------------------------------------------------------------
// CSR build (once per call, shared by all 3 layers)
// ---------------------------------------------------------------------------
__global__ __launch_bounds__(256) void k_deg_count(const int* __restrict__ dst,
                                                   int* __restrict__ degcnt, int e) {
    int i = blockIdx.x * 256 + threadIdx.x;
    if (i < e) atomicAdd(&degcnt[dst[i]], 1);
}

__global__ __launch_bounds__(256) void k_blocksum(const int* __restrict__ degcnt,
                                                  int* __restrict__ bsum, int n) {
    __shared__ int part[256];
    const int tid = threadIdx.x;
    const int gid = blockIdx.x * 256 + tid;
    part[tid] = (gid < n) ? degcnt[gid] : 0;
    __syncthreads();
    for (int off = 128; off > 0; off >>= 1) {
        if (tid < off) part[tid] += part[tid + off];
        __syncthreads();
    }
    if (tid == 0) bsum[blockIdx.x] = part[0];
}

__global__ __launch_bounds__(256) void k_scanb(const int* __restrict__ bsum,
                                               int* __restrict__ boff) {
    __shared__ int part[256];
    const int tid = threadIdx.x;
    part[tid] = (tid < NB_SCAN) ? bsum[tid] : 0;
    __syncthreads();
    for (int off = 1; off < 256; off <<= 1) {
        int v = (tid >= off) ? part[tid - off] : 0;
        __syncthreads();
        part[tid] += v;
        __syncthreads();
    }
    if (tid < NB_SCAN) boff[tid] = (tid == 0) ? 0 : part[tid - 1];
}

__global__ __launch_bounds__(256) void k_rowstart(const int* __restrict__ degcnt,
                                                  const int* __restrict__ boff,
                                                  int* __restrict__ rowstart,
                                                  float* __restrict__ dinv, int n) {
    __shared__ int part[256];
    const int tid = threadIdx.x;
    const int gid = blockIdx.x * 256 + tid;
    const int d = (gid < n) ? degcnt[gid] : 0;
    part[tid] = d;
    __syncthreads();
    for (int off = 1; off < 256; off <<= 1) {
        int v = (tid >= off) ? part[tid - off] : 0;
        __syncthreads();
        part[tid] += v;
        __syncthreads();
    }
    if (gid < n) {
        rowstart[gid] = boff[blockIdx.x] + part[tid] - d;   // exclusive
        dinv[gid] = rsqrtf((float)(d + 1));                 // +1 self loop
    }
    if (gid == 0) rowstart[n] = N_EDGES;
}

__global__ __launch_bounds__(256) void k_bin(const int* __restrict__ src,
                                             const int* __restrict__ dst,
                                             const int* __restrict__ rowstart,
                                             int* __restrict__ cursor,
                                             int* __restrict__ esrc, int e) {
    int i = blockIdx.x * 256 + threadIdx.x;
    if (i < e) {
        int d = dst[i];
        int pos = rowstart[d] + atomicAdd(&cursor[d], 1);
        esrc[pos] = src[i];
    }
}

// ---------------------------------------------------------------------------
// GEMM + row-scale + FP16 PACK: C[i][:] = fp16( ((RELU? relu(A):A)[i] @ W) * dinv[i] )
// W in LDS; A (f32) read directly from global (row broadcast via L1).
// C stored as packed half4 (uint2) per thread -> halves write traffic and,
// crucially, halves the line count of every downstream gather.
// ---------------------------------------------------------------------------
template<int K, bool RELU>
__global__ __launch_bounds__(256) void k_gemm(const float* __restrict__ A,
                                              const float* __restrict__ W,
                                              const float* __restrict__ dinv,
                                              __half* __restrict__ C, int n) {
    constexpr int CG   = K / 4;            // 4-col groups (32 or 16)
    constexpr int RG   = 256 / CG;
    constexpr int ROWS = RG * 4;
    __shared__ float4 Wl4[128 * CG];

    const int tid  = threadIdx.x;
    const int row0 = blockIdx.x * ROWS;

    constexpr int WV = (128 * CG) / 256;
    const float4* W4 = (const float4*)W;
#pragma unroll
    for (int i = 0; i < WV; ++i) Wl4[tid + i * 256] = W4[tid + i * 256];
    __syncthreads();

    const int cg = tid % CG;
    const int rg = tid / CG;
    const int gr = row0 + rg * 4;

    const float4* p0 = (const float4*)A + (size_t)min(gr + 0, n - 1) * 32;
    const float4* p1 = (const float4*)A + (size_t)min(gr + 1, n - 1) * 32;
    const float4* p2 = (const float4*)A + (size_t)min(gr + 2, n - 1) * 32;
    const float4* p3 = (const float4*)A + (size_t)min(gr + 3, n - 1) * 32;

    float4 acc0 = make_float4(0.f, 0.f, 0.f, 0.f);
    float4 acc1 = acc0, acc2 = acc0, acc3 = acc0;

#pragma unroll 2
    for (int m4 = 0; m4 < 32; ++m4) {
        float4 a0 = p0[m4], a1 = p1[m4], a2 = p2[m4], a3 = p3[m4];
        if (RELU) {
            a0.x = fmaxf(a0.x, 0.f); a0.y = fmaxf(a0.y, 0.f); a0.z = fmaxf(a0.z, 0.f); a0.w = fmaxf(a0.w, 0.f);
            a1.x = fmaxf(a1.x, 0.f); a1.y = fmaxf(a1.y, 0.f); a1.z = fmaxf(a1.z, 0.f); a1.w = fmaxf(a1.w, 0.f);
            a2.x = fmaxf(a2.x, 0.f); a2.y = fmaxf(a2.y, 0.f); a2.z = fmaxf(a2.z, 0.f); a2.w = fmaxf(a2.w, 0.f);
            a3.x = fmaxf(a3.x, 0.f); a3.y = fmaxf(a3.y, 0.f); a3.z = fmaxf(a3.z, 0.f); a3.w = fmaxf(a3.w, 0.f);
        }
        const float4 w0 = Wl4[(m4 * 4 + 0) * CG + cg];
        const float4 w1 = Wl4[(m4 * 4 + 1) * CG + cg];
        const float4 w2 = Wl4[(m4 * 4 + 2) * CG + cg];
        const float4 w3 = Wl4[(m4 * 4 + 3) * CG + cg];

#define ROW_STEP(A_, ACC_)                                    \
        {                                                     \
            ACC_.x = fmaf(A_.x, w0.x, ACC_.x);                \
            ACC_.x = fmaf(A_.y, w1.x, ACC_.x);                \
            ACC_.x = fmaf(A_.z, w2.x, ACC_.x);                \
            ACC_.x = fmaf(A_.w, w3.x, ACC_.x);                \
            ACC_.y = fmaf(A_.x, w0.y, ACC_.y);                \
            ACC_.y = fmaf(A_.y, w1.y, ACC_.y);                \
            ACC_.y = fmaf(A_.z, w2.y, ACC_.y);                \
            ACC_.y = fmaf(A_.w, w3.y, ACC_.y);                \
            ACC_.z = fmaf(A_.x, w0.z, ACC_.z);                \
            ACC_.z = fmaf(A_.y, w1.z, ACC_.z);                \
            ACC_.z = fmaf(A_.z, w2.z, ACC_.z);                \
            ACC_.z = fmaf(A_.w, w3.z, ACC_.z);                \
            ACC_.w = fmaf(A_.x, w0.w, ACC_.w);                \
            ACC_.w = fmaf(A_.y, w1.w, ACC_.w);                \
            ACC_.w = fmaf(A_.z, w2.w, ACC_.w);                \
            ACC_.w = fmaf(A_.w, w3.w, ACC_.w);                \
        }
        ROW_STEP(a0, acc0);
        ROW_STEP(a1, acc1);
        ROW_STEP(a2, acc2);
        ROW_STEP(a3, acc3);
#undef ROW_STEP
    }

    {
        float d0 = dinv[min(gr + 0, n - 1)];
        float d1 = dinv[min(gr + 1, n - 1)];
        float d2 = dinv[min(gr + 2, n - 1)];
        float d3 = dinv[min(gr + 3, n - 1)];
        union { __half2 h2[2]; uint2 u; } pk0, pk1, pk2, pk3;
        pk0.h2[0] = __floats2half2_rn(acc0.x * d0, acc0.y * d0);
        pk0.h2[1] = __floats2half2_rn(acc0.z * d0, acc0.w * d0);
        pk1.h2[0] = __floats2half2_rn(acc1.x * d1, acc1.y * d1);
        pk1.h2[1] = __floats2half2_rn(acc1.z * d1, acc1.w * d1);
        pk2.h2[0] = __floats2half2_rn(acc2.x * d2, acc2.y * d2);
        pk2.h2[1] = __floats2half2_rn(acc2.z * d2, acc2.w * d2);
        pk3.h2[0] = __floats2half2_rn(acc3.x * d3, acc3.y * d3);
        pk3.h2[1] = __floats2half2_rn(acc3.z * d3, acc3.w * d3);
        // row of K halves = CG uint2's; thread cg owns cols 4cg..4cg+3
        if (gr + 0 < n) ((uint2*)C)[(size_t)(gr + 0) * CG + cg] = pk0.u;
        if (gr + 1 < n) ((uint2*)C)[(size_t)(gr + 1) * CG + cg] = pk1.u;
        if (gr + 2 < n) ((uint2*)C)[(size_t)(gr + 2) * CG + cg] = pk2.u;
        if (gr + 3 < n) ((uint2*)C)[(size_t)(gr + 3) * CG + cg] = pk3.u;
    }
}

// ---------------------------------------------------------------------------
// Gather aggregation v4: fp16 h', ONE NODE PER 32-LANE GROUP, 8-deep batch.
//   out[d][:] = dinv[d] * ( h'[d][:] + sum_{e: dst=d} h'[src_e][:] ) + b
// K=128: lane owns 4 cols (uint2 = half4). K=64: 2 cols (uint = half2).
// ---------------------------------------------------------------------------
template<int K>
__global__ __launch_bounds__(256) void k_aggregate(const __half* __restrict__ h,
                                                   const int* __restrict__ rowstart,
                                                   const int* __restrict__ esrc,
                                                   const float* __restrict__ dinv,
                                                   const float* __restrict__ b,
                                                   float* __restrict__ out, int n) {
    constexpr int VEC = K / 32;            // halves per lane (4 or 2)
    const int tid  = threadIdx.x;
    const int l5   = tid & 31;
    const int base = tid & 32;             // half-offset within the wave
    const int node = blockIdx.x * 8 + (tid >> 5);
    if (node >= n) return;

    float a0, a1, a2 = 0.f, a3 = 0.f;
    if (VEC == 4) {
        uint2 raw = ((const uint2*)h)[(size_t)node * 32 + l5];
        union { uint2 u; __half2 h2[2]; } c; c.u = raw;
        float2 lo = __half22float2(c.h2[0]);
        float2 hi = __half22float2(c.h2[1]);
        a0 = lo.x; a1 = lo.y; a2 = hi.x; a3 = hi.y;
    } else {
        uint raw = ((const uint*)h)[(size_t)node * 32 + l5];
        union { uint u; __half2 h2; } c; c.u = raw;
        float2 lo = __half22float2(c.h2);
        a0 = lo.x; a1 = lo.y;
    }

    int row = rowstart[node];
    const int end = rowstart[node + 1];

#define GATHER(SRC_, OK_)                                                     \
    if (VEC == 4) {                                                           \
        uint2 raw = make_uint2(0u, 0u);                                       \
        if (OK_) raw = ((const uint2*)h)[(size_t)(SRC_) * 32 + l5];           \
        union { uint2 u; __half2 h2[2]; } c; c.u = raw;                       \
        float2 lo = __half22float2(c.h2[0]);                                  \
        float2 hi = __half22float2(c.h2[1]);                                  \
        a0 += lo.x; a1 += lo.y; a2 += hi.x; a3 += hi.y;                       \
    } else {                                                                  \
        uint raw = 0u;                                                        \
        if (OK_) raw = ((const uint*)h)[(size_t)(SRC_) * 32 + l5];            \
        union { uint u; __half2 h2; } c; c.u = raw;                           \
        float2 lo = __half22float2(c.h2);                                     \
        a0 += lo.x; a1 += lo.y;                                               \
    }

    while (row < end) {
        int cnt = end - row;
        if (cnt > 32) cnt = 32;
        int s_l = (l5 < cnt) ? esrc[row + l5] : 0;
        for (int jj = 0; jj < cnt; jj += 8) {
            const int i0 = jj + 0, i1 = jj + 1, i2 = jj + 2, i3 = jj + 3;
            const int i4 = jj + 4, i5 = jj + 5, i6 = jj + 6, i7 = jj + 7;
            const int s0 = __shfl(s_l, base + i0);
            const int s1 = __shfl(s_l, base + i1);
            const int s2 = __shfl(s_l, base + i2);
            const int s3 = __shfl(s_l, base + i3);
            const int s4 = __shfl(s_l, base + i4);
            const int s5 = __shfl(s_l, base + i5);
            const int s6 = __shfl(s_l, base + i6);
            const int s7 = __shfl(s_l, base + i7);
            GATHER(s0, i0 < cnt);
            GATHER(s1, i1 < cnt);
            GATHER(s2, i2 < cnt);
            GATHER(s3, i3 < cnt);
            GATHER(s4, i4 < cnt);
            GATHER(s5, i5 < cnt);
            GATHER(s6, i6 < cnt);
            GATHER(s7, i7 < cnt);
        }
        row += cnt;
    }
#undef GATHER

    const float dd = dinv[node];
    if (VEC == 4) {
        float4 bb = ((const float4*)b)[l5];
        float4 o;
        o.x = a0 * dd + bb.x;
        o.y = a1 * dd + bb.y;
        o.z = a2 * dd + bb.z;
        o.w = a3 * dd + bb.w;
        ((float4*)out)[(size_t)node * 32 + l5] = o;
    } else {
        float2 bb = ((const float2*)b)[l5];
        float2 o;
        o.x = a0 * dd + bb.x;
        o.y = a1 * dd + bb.y;
        ((float2*)out)[(size_t)node * 32 + l5] = o;
    }
}

// ---------------------------------------------------------------------------
extern "C" void kernel_launch(void* const* d_in, const int* in_sizes, int n_in,
                              void* d_out, int out_size, void* d_ws, size_t ws_size,
                              hipStream_t stream) {
    const float* x  = (const float*)d_in[0];
    const int*   ei = (const int*)d_in[1];
    const float* W1 = (const float*)d_in[2];
    const float* b1 = (const float*)d_in[3];
    const float* W2 = (const float*)d_in[4];
    const float* b2 = (const float*)d_in[5];
    const float* W3 = (const float*)d_in[6];
    const float* b3 = (const float*)d_in[7];
    float* out = (float*)d_out;

    const int* src = ei;
    const int* dst = ei + N_EDGES;

    char* ws = (char*)d_ws;
    size_t off = 0;
    auto alloc = [&](size_t bytes) {
        void* p = ws + off;
        off += (bytes + 255) & ~(size_t)255;
        return p;
    };
    int*    degcnt   = (int*)alloc((size_t)N_NODES * 2 * 4);  // degcnt + cursor
    int*    cursor   = degcnt + N_NODES;
    int*    rowstart = (int*)alloc((N_NODES + 1) * 4);
    float*  dinv     = (float*)alloc(N_NODES * 4);
    int*    bsum     = (int*)alloc(NB_SCAN * 4);
    int*    boff     = (int*)alloc(NB_SCAN * 4);
    int*    esrc     = (int*)alloc((size_t)N_EDGES * 4);
    __half* hbuf     = (__half*)alloc((size_t)N_NODES * 128 * 2);  // fp16 h'
    float*  abuf     = (float*)alloc((size_t)N_NODES * 128 * 4);

    const int n = N_NODES, e = N_EDGES;

    // --- CSR build (once; reused by all layers) ---
    hipMemsetAsync(degcnt, 0, (size_t)N_NODES * 2 * 4, stream);
    k_deg_count<<<CEILDIV(e, 256), 256, 0, stream>>>(dst, degcnt, e);
    k_blocksum<<<NB_SCAN, 256, 0, stream>>>(degcnt, bsum, n);
    k_scanb<<<1, 256, 0, stream>>>(bsum, boff);
    k_rowstart<<<NB_SCAN, 256, 0, stream>>>(degcnt, boff, rowstart, dinv, n);
    k_bin<<<CEILDIV(e, 256), 256, 0, stream>>>(src, dst, rowstart, cursor, esrc, e);

    // --- layer 1 ---
    k_gemm<128, false><<<CEILDIV(n, 32), 256, 0, stream>>>(x, W1, dinv, hbuf, n);
    k_aggregate<128><<<CEILDIV(n, 8), 256, 0, stream>>>(hbuf, rowstart, esrc, dinv, b1, abuf, n);

    // --- layer 2 ---
    k_gemm<128, true><<<CEILDIV(n, 32), 256, 0, stream>>>(abuf, W2, dinv, hbuf, n);
    k_aggregate<128><<<CEILDIV(n, 8), 256, 0, stream>>>(hbuf, rowstart, esrc, dinv, b2, abuf, n);

    // --- layer 3 (K=64) ---
    k_gemm<64, true><<<CEILDIV(n, 64), 256, 0, stream>>>(abuf, W3, dinv, hbuf, n);
    k_aggregate<64><<<CEILDIV(n, 8), 256, 0, stream>>>(hbuf, rowstart, esrc, dinv, b3, out, n);
}